// Round 4
// baseline (361.846 us; speedup 1.0000x reference)
//
#include <hip/hip_runtime.h>

// N=100000 nodes, E=1250000 edges, all dims 64.
// R13 = R12 resubmit (container failed twice; audit found no kernel fault) with
// hardening: inline-asm literal s_waitcnt vmcnt(N) (proven pattern) instead of
// the builtin, and sched_barrier(0) pinned right after staging issue.
// Design (from R12):
//  (a) meta (csr+pk) hoisted: whole <=256-edge range pre-loaded into 8 resident
//      VGPRs per wave (rare dynamic path beyond).
//  (b) staging via global_load_lds (dest = uniform base + lane*16 == our
//      conflict-free subtiled map via pre-swizzled per-lane global src).
//  (c) LDS double-buffer + counted s_waitcnt vmcnt(PASSES): chunk k+1 loads
//      stay in flight while chunk k computes. Never vmcnt(0) in the loop.
//  (d) 128-thread blocks (no barriers in this kernel).

#define SCAN_CHUNK 2048

typedef __attribute__((ext_vector_type(8))) short short8;   // 8 bf16 = 4 VGPRs
typedef __attribute__((ext_vector_type(4))) short short4v;  // 4 bf16 = 2 VGPRs
typedef __attribute__((ext_vector_type(4))) float floatx4;  // MFMA C/D

__device__ __forceinline__ unsigned short f2bf(float f) {
    unsigned int u = __float_as_uint(f);
    unsigned int r = u + 0x7FFFu + ((u >> 16) & 1u);  // round-to-nearest-even
    return (unsigned short)(r >> 16);
}
__device__ __forceinline__ float bf2f(unsigned short h) {
    return __uint_as_float(((unsigned int)h) << 16);
}

__device__ __forceinline__ unsigned lds_addr(const void* p) {
    return (unsigned)(unsigned long long)(__attribute__((address_space(3))) const char*)p;
}

__device__ __forceinline__ void gload_lds16(const void* g, void* l) {
    __builtin_amdgcn_global_load_lds(
        (const __attribute__((address_space(1))) unsigned int*)g,
        (__attribute__((address_space(3))) unsigned int*)l, 16, 0, 0);
}

template<int NN>
__device__ __forceinline__ void wait_vmcnt() {
    if constexpr (NN == 8)      asm volatile("s_waitcnt vmcnt(8)" ::: "memory");
    else if constexpr (NN == 4) asm volatile("s_waitcnt vmcnt(4)" ::: "memory");
    else                        asm volatile("s_waitcnt vmcnt(0)" ::: "memory");
}

__device__ __forceinline__ short8 cat44(short4v lo, short4v hi) {
    short8 r;
    r[0] = lo[0]; r[1] = lo[1]; r[2] = lo[2]; r[3] = lo[3];
    r[4] = hi[0]; r[5] = hi[1]; r[6] = hi[2]; r[7] = hi[3];
    return r;
}

// Read 4 B-frags (col-tiles CTB..CTB+3) for this lane's k-group via HW transpose.
// LDS holds 32xROWSH bf16 tile subtiled [k/4][f/16][4][16]; subtile s at byte s*128.
// a0 = wb_base + (q*2*NF)*128 + (lane&15)*8.
template<int NF, int CTB>
__device__ __forceinline__ void tr_read4(unsigned a0, short8 bf[4]) {
    short4v l0, h0, l1, h1, l2, h2, l3, h3;
    asm volatile(
        "ds_read_b64_tr_b16 %0, %8 offset:%9\n\t"
        "ds_read_b64_tr_b16 %1, %8 offset:%10\n\t"
        "ds_read_b64_tr_b16 %2, %8 offset:%11\n\t"
        "ds_read_b64_tr_b16 %3, %8 offset:%12\n\t"
        "ds_read_b64_tr_b16 %4, %8 offset:%13\n\t"
        "ds_read_b64_tr_b16 %5, %8 offset:%14\n\t"
        "ds_read_b64_tr_b16 %6, %8 offset:%15\n\t"
        "ds_read_b64_tr_b16 %7, %8 offset:%16\n\t"
        "s_waitcnt lgkmcnt(0)"
        : "=&v"(l0), "=&v"(h0), "=&v"(l1), "=&v"(h1),
          "=&v"(l2), "=&v"(h2), "=&v"(l3), "=&v"(h3)
        : "v"(a0),
          "i"((0 * NF + CTB + 0) * 128), "i"((1 * NF + CTB + 0) * 128),
          "i"((0 * NF + CTB + 1) * 128), "i"((1 * NF + CTB + 1) * 128),
          "i"((0 * NF + CTB + 2) * 128), "i"((1 * NF + CTB + 2) * 128),
          "i"((0 * NF + CTB + 3) * 128), "i"((1 * NF + CTB + 3) * 128)
        : "memory");
    bf[0] = cat44(l0, h0);
    bf[1] = cat44(l1, h1);
    bf[2] = cat44(l2, h2);
    bf[3] = cat44(l3, h3);
}

// count + record per-edge rank (return of atomicAdd) -> atomic-free fill
__global__ void k_count(const int* __restrict__ ei, int E, int* __restrict__ cnt,
                        int* __restrict__ rank) {
    int i = blockIdx.x * blockDim.x + threadIdx.x;
    int e = i * 4;
    if (e + 4 <= E) {
        int4 d = *(const int4*)&ei[E + e];
        int4 r;
        r.x = atomicAdd(&cnt[d.x], 1);
        r.y = atomicAdd(&cnt[d.y], 1);
        r.z = atomicAdd(&cnt[d.z], 1);
        r.w = atomicAdd(&cnt[d.w], 1);
        *(int4*)&rank[e] = r;
    } else {
        for (int j = e; j < E; ++j) rank[j] = atomicAdd(&cnt[ei[E + j]], 1);
    }
}

// scan over (cnt[i] + 1): one self-loop slot per node appended to its edge range
__global__ void k_scan_reduce(const int* __restrict__ cnt, int N, int* __restrict__ blockSums) {
    __shared__ int lds[256];
    int base = blockIdx.x * SCAN_CHUNK;
    int t = threadIdx.x;
    int s = 0;
    for (int j = 0; j < 8; ++j) {
        int idx = base + t * 8 + j;
        if (idx < N) s += cnt[idx] + 1;
    }
    lds[t] = s;
    __syncthreads();
    for (int d = 128; d > 0; d >>= 1) {
        if (t < d) lds[t] += lds[t + d];
        __syncthreads();
    }
    if (t == 0) blockSums[blockIdx.x] = lds[0];
}

__global__ void k_scan_spine(int* __restrict__ blockSums, int B) {
    if (threadIdx.x == 0 && blockIdx.x == 0) {
        int run = 0;
        for (int b = 0; b < B; ++b) { int v = blockSums[b]; blockSums[b] = run; run += v; }
    }
}

__global__ void k_scan_write(const int* __restrict__ cnt, int N,
                             const int* __restrict__ blockSums,
                             int* __restrict__ offs, float* __restrict__ dinv) {
    __shared__ int lds[256];
    int base = blockIdx.x * SCAN_CHUNK;
    int t = threadIdx.x;
    int v[8];
    int s = 0;
    for (int j = 0; j < 8; ++j) {
        int idx = base + t * 8 + j;
        v[j] = (idx < N) ? cnt[idx] : 0;
        s += (idx < N) ? v[j] + 1 : 0;
    }
    lds[t] = s;
    __syncthreads();
    for (int d = 1; d < 256; d <<= 1) {
        int x = (t >= d) ? lds[t - d] : 0;
        __syncthreads();
        lds[t] += x;
        __syncthreads();
    }
    int excl = (t == 0) ? 0 : lds[t - 1];
    int run = blockSums[blockIdx.x] + excl;
    for (int j = 0; j < 8; ++j) {
        int idx = base + t * 8 + j;
        if (idx < N) {
            offs[idx] = run;
            run += v[j] + 1;
            dinv[idx] = rsqrtf((float)v[j] + 1.0f);
            if (idx == N - 1) offs[N] = run;  // total incl. self slots
        }
    }
}

// atomic-free fill: pos = offs[dst] + rank[e]; also emits pk = (dst&15)<<16 | bf16(ew)
__global__ void k_fill(const int* __restrict__ ei, int E, const int* __restrict__ offs,
                       const int* __restrict__ rank, const float* __restrict__ dinv,
                       int* __restrict__ csr, unsigned int* __restrict__ pk, int use_pk) {
    int i = blockIdx.x * blockDim.x + threadIdx.x;
    int e = i * 4;
    if (e + 4 <= E) {
        int4 s = *(const int4*)&ei[e];
        int4 d = *(const int4*)&ei[E + e];
        int4 r = *(const int4*)&rank[e];
        int p0 = offs[d.x] + r.x, p1 = offs[d.y] + r.y;
        int p2 = offs[d.z] + r.z, p3 = offs[d.w] + r.w;
        csr[p0] = s.x; csr[p1] = s.y; csr[p2] = s.z; csr[p3] = s.w;
        if (use_pk) {
            pk[p0] = ((unsigned)(d.x & 15) << 16) | f2bf(dinv[s.x] * dinv[d.x]);
            pk[p1] = ((unsigned)(d.y & 15) << 16) | f2bf(dinv[s.y] * dinv[d.y]);
            pk[p2] = ((unsigned)(d.z & 15) << 16) | f2bf(dinv[s.z] * dinv[d.z]);
            pk[p3] = ((unsigned)(d.w & 15) << 16) | f2bf(dinv[s.w] * dinv[d.w]);
        }
    } else {
        for (int j = e; j < E; ++j) {
            int dd = ei[E + j];
            int p = offs[dd] + rank[j];
            csr[p] = ei[j];
            if (use_pk) pk[p] = ((unsigned)(dd & 15) << 16) | f2bf(dinv[ei[j]] * dinv[dd]);
        }
    }
}

// self-loop edge at offs[i]+cnt[i]: GCN weight di^2, bit20 = SAGE-exclude
__global__ void k_self(const int* __restrict__ offs, const int* __restrict__ cnt,
                       const float* __restrict__ dinv,
                       int* __restrict__ csr, unsigned int* __restrict__ pk, int N) {
    int i = blockIdx.x * blockDim.x + threadIdx.x;
    if (i < N) {
        int pos = offs[i] + cnt[i];
        float di = dinv[i];
        csr[pos] = i;
        pk[pos] = ((unsigned)(i & 15) << 16) | (1u << 20) | f2bf(di * di);
    }
}

__global__ void k_xtobf16(const float* __restrict__ x, unsigned short* __restrict__ xb, int total) {
    int i = blockIdx.x * blockDim.x + threadIdx.x;
    int e = i * 8;
    if (e + 8 <= total) {
        float4 a = *(const float4*)&x[e];
        float4 b = *(const float4*)&x[e + 4];
        short8 o;
        o[0] = (short)f2bf(a.x); o[1] = (short)f2bf(a.y);
        o[2] = (short)f2bf(a.z); o[3] = (short)f2bf(a.w);
        o[4] = (short)f2bf(b.x); o[5] = (short)f2bf(b.y);
        o[6] = (short)f2bf(b.z); o[7] = (short)f2bf(b.w);
        *(short8*)&xb[e] = o;
    } else {
        for (int j = e; j < total; ++j) xb[j] = f2bf(x[j]);
    }
}

// ===================== MFMA SpMM gather (async pipelined) =====================
// One wave per 16 dst nodes; 2 waves/block; no barriers. Edges incl. self-loops
// contiguous in [offs[base], offs[base+16)). Per 32-edge chunk: global_load_lds
// stages 32 src rows into LDS (linear lane*16 dest == subtiled layout via
// pre-swizzled per-lane global src); A-frags from resident meta regs via shfl;
// counted vmcnt(PASSES) keeps next chunk's loads in flight during MFMA.
template<int ROWSH>
__launch_bounds__(128)
__global__ void k_gatherM(const unsigned short* __restrict__ feat,
                          const int* __restrict__ csr,
                          const unsigned int* __restrict__ pk,
                          const int* __restrict__ offs, const int* __restrict__ cnt,
                          unsigned short* __restrict__ agg, int N) {
    constexpr int NF = ROWSH / 16;      // f-subtiles per edge row (4 or 8)
    constexpr int LPR = ROWSH / 8;      // lanes per staged row
    constexpr int EPP = 64 / LPR;       // edges per staging pass
    constexpr int PASSES = 32 / EPP;    // gll instructions per chunk (4 or 8)

    __shared__ unsigned short sbuf[2][2][32 * ROWSH];  // [wave][buf]

    const int lane = threadIdx.x & 63;
    const int wv = threadIdx.x >> 6;
    const int base = blockIdx.x * 32 + wv * 16;
    if (base >= N) return;

    const int q = lane >> 4;
    const int d16 = lane & 15;

    // conflict-free staging map: lane L sources the 16B that belongs at byte
    // p*1024 + 16L of the subtiled LDS image (bijection per 1024B pass block).
    const int parity = lane & 1;
    const int ei_low = (lane >> 1) & 3;
    const int sf_sub = (lane >> 3) & (NF - 1);
    const int ei_high = (NF == 8) ? 0 : (lane >> 5);
    const int eid = ei_high * 4 + ei_low;
    const int sf = sf_sub * 16 + parity * 8;

    const int elo = offs[base];
    const int ehi = offs[min(base + 16, N)];
    const int emax = ehi - 1;
    const int nch = (ehi - elo + 31) >> 5;

    // ---- resident meta: 4 windows of 64 edges (covers 8 chunks = 256 edges) ----
    int cM0, cM1, cM2, cM3;
    unsigned pM0, pM1, pM2, pM3;
    {
        int i0 = elo + lane;
        int i1 = i0 + 64, i2 = i0 + 128, i3 = i0 + 192;
        cM0 = csr[i0 <= emax ? i0 : emax];
        cM1 = csr[i1 <= emax ? i1 : emax];
        cM2 = csr[i2 <= emax ? i2 : emax];
        cM3 = csr[i3 <= emax ? i3 : emax];
        unsigned t0 = pk[i0 <= emax ? i0 : emax];
        unsigned t1 = pk[i1 <= emax ? i1 : emax];
        unsigned t2 = pk[i2 <= emax ? i2 : emax];
        unsigned t3 = pk[i3 <= emax ? i3 : emax];
        pM0 = (i0 < ehi) ? t0 : 0x00100000u;
        pM1 = (i1 < ehi) ? t1 : 0x00100000u;
        pM2 = (i2 < ehi) ? t2 : 0x00100000u;
        pM3 = (i3 < ehi) ? t3 : 0x00100000u;
    }

    floatx4 accg[4], accs[4];
#pragma unroll
    for (int i = 0; i < 4; ++i) {
        accg[i] = floatx4{0.f, 0.f, 0.f, 0.f};
        accs[i] = floatx4{0.f, 0.f, 0.f, 0.f};
    }

    unsigned short* wb0 = &sbuf[wv][0][0];
    unsigned short* wb1 = &sbuf[wv][1][0];
    const unsigned a0base = (unsigned)(q * 2 * NF) * 128u + (unsigned)d16 * 8u;
    const unsigned a0_0 = lds_addr(wb0) + a0base;
    const unsigned a0_1 = lds_addr(wb1) + a0base;

    auto getmeta = [&](int c, int& cv, unsigned& pv, int& wofs) {
        int rc = c >> 1;
        if (rc < 4) {
            wofs = (c & 1) << 5;
            cv = (rc == 0) ? cM0 : (rc == 1) ? cM1 : (rc == 2) ? cM2 : cM3;
            pv = (rc == 0) ? pM0 : (rc == 1) ? pM1 : (rc == 2) ? pM2 : pM3;
        } else {  // rare: range > 256 edges
            int idx = elo + (c << 5) + lane;
            int idc = idx <= emax ? idx : emax;
            cv = csr[idc];
            unsigned t = pk[idc];
            pv = (idx < ehi) ? t : 0x00100000u;
            wofs = 0;
        }
    };

    auto issue = [&](unsigned short* dst, int cv, int wofs) {
#pragma unroll
        for (int p = 0; p < PASSES; ++p) {
            int src = __shfl(cv, wofs + p * EPP + eid, 64);
            gload_lds16(&feat[(size_t)src * ROWSH + sf], dst + p * 512);
        }
        __builtin_amdgcn_sched_barrier(0);  // pin gll issue order vs later waits
    };

    int cv; unsigned pv; int wofs;
    getmeta(0, cv, pv, wofs);
    issue(wb0, cv, wofs);
    unsigned pvC = pv; int wofsC = wofs;

    int cur = 0;
    for (int c = 0; c < nch; ++c) {
        bool pf = (c + 1 < nch);
        if (pf) {
            getmeta(c + 1, cv, pv, wofs);
            issue(cur ? wb0 : wb1, cv, wofs);
        }
        // A-frags for chunk c (register-only; overlaps in-flight loads)
        short8 aG, aS;
#pragma unroll
        for (int j = 0; j < 8; ++j) {
            unsigned u = (unsigned)__shfl((int)pvC, wofsC + q * 8 + j, 64);
            unsigned hi = u >> 16;
            bool match = (int)(hi & 15u) == d16;
            aG[j] = match ? (short)(u & 0xFFFFu) : (short)0;
            aS[j] = (match && !(hi & 16u)) ? (short)0x3F80 : (short)0;
        }
        if (pf) wait_vmcnt<PASSES>();  // chunk c landed; c+1 stays in flight
        else    wait_vmcnt<0>();       // drain last chunk
        __builtin_amdgcn_sched_barrier(0);

        const unsigned a0 = cur ? a0_1 : a0_0;
        short8 bG[4];
        tr_read4<NF, 0>(a0, bG);
#pragma unroll
        for (int ct = 0; ct < 4; ++ct)
            accg[ct] = __builtin_amdgcn_mfma_f32_16x16x32_bf16(aG, bG[ct], accg[ct], 0, 0, 0);
        if constexpr (NF == 8) {
            short8 bS[4];
            tr_read4<NF, 4>(a0, bS);
#pragma unroll
            for (int ct = 0; ct < 4; ++ct)
                accs[ct] = __builtin_amdgcn_mfma_f32_16x16x32_bf16(aS, bS[ct], accs[ct], 0, 0, 0);
        } else {
#pragma unroll
            for (int ct = 0; ct < 4; ++ct)
                accs[ct] = __builtin_amdgcn_mfma_f32_16x16x32_bf16(aS, bG[ct], accs[ct], 0, 0, 0);
        }
        pvC = pv; wofsC = wofs;
        cur ^= 1;
    }

    // ---- epilogue: C/D layout row=(q*4+r), col=d16 ----
#pragma unroll
    for (int r = 0; r < 4; ++r) {
        int node = base + q * 4 + r;
        if (node < N) {
            float rn = 1.0f / fmaxf((float)cnt[node], 1.0f);
#pragma unroll
            for (int ct = 0; ct < 4; ++ct) {
                agg[(size_t)node * 128 + ct * 16 + d16]      = f2bf(accg[ct][r]);
                agg[(size_t)node * 128 + 64 + ct * 16 + d16] = f2bf(accs[ct][r] * rn);
            }
        }
    }
}

// ===================== fallback scalar gathers (ws-size guard) =====================
// NOTE: offs now includes one self slot per node; fallbacks read only the first
// cnt[] entries of each node's range, so they remain correct.
__device__ __forceinline__ void xor_reduce8(float4& a, float4& b) {
    a.x += __shfl_xor(a.x, 16, 64); a.y += __shfl_xor(a.y, 16, 64);
    a.z += __shfl_xor(a.z, 16, 64); a.w += __shfl_xor(a.w, 16, 64);
    b.x += __shfl_xor(b.x, 16, 64); b.y += __shfl_xor(b.y, 16, 64);
    b.z += __shfl_xor(b.z, 16, 64); b.w += __shfl_xor(b.w, 16, 64);
    a.x += __shfl_xor(a.x, 32, 64); a.y += __shfl_xor(a.y, 32, 64);
    a.z += __shfl_xor(a.z, 32, 64); a.w += __shfl_xor(a.w, 32, 64);
    b.x += __shfl_xor(b.x, 32, 64); b.y += __shfl_xor(b.y, 32, 64);
    b.z += __shfl_xor(b.z, 32, 64); b.w += __shfl_xor(b.w, 32, 64);
}

__device__ __forceinline__ float red16(float v) {
    v += __shfl_xor(v, 1, 64);
    v += __shfl_xor(v, 2, 64);
    v += __shfl_xor(v, 4, 64);
    v += __shfl_xor(v, 8, 64);
    return v;
}

__global__ void k_gather1_f32(const float* __restrict__ x, const int* __restrict__ csr,
                              const int* __restrict__ offs, const int* __restrict__ cnt,
                              const float* __restrict__ dinv,
                              unsigned short* __restrict__ agg, int N) {
    int lane = threadIdx.x & 63;
    int wave = threadIdx.x >> 6;
    int node = blockIdx.x * 4 + wave;
    if (node >= N) return;
    int c = lane & 15, grp = lane >> 4;

    int st = offs[node];
    int cn = cnt[node];
    float di = dinv[node];

    float4 aA = {0.f, 0.f, 0.f, 0.f}, aB = {0.f, 0.f, 0.f, 0.f};
    for (int e = 0; e < cn; e += 8) {
        int i0 = e + grp, i1 = e + 4 + grp;
        float m0 = (i0 < cn) ? 1.f : 0.f;
        float m1 = (i1 < cn) ? 1.f : 0.f;
        int s0 = csr[st + (i0 < cn ? i0 : cn - 1)];
        int s1 = csr[st + (i1 < cn ? i1 : cn - 1)];
        float w0 = m0 * dinv[s0];
        float w1 = m1 * dinv[s1];
        float4 v0 = *(const float4*)&x[(size_t)s0 * 64 + 4 * c];
        float4 v1 = *(const float4*)&x[(size_t)s1 * 64 + 4 * c];
        aA.x += w0 * v0.x + w1 * v1.x; aA.y += w0 * v0.y + w1 * v1.y;
        aA.z += w0 * v0.z + w1 * v1.z; aA.w += w0 * v0.w + w1 * v1.w;
        aB.x += m0 * v0.x + m1 * v1.x; aB.y += m0 * v0.y + m1 * v1.y;
        aB.z += m0 * v0.z + m1 * v1.z; aB.w += m0 * v0.w + m1 * v1.w;
    }
    xor_reduce8(aA, aB);

    if (grp == 0) {
        float4 sq = *(const float4*)&x[(size_t)node * 64 + 4 * c];
        float d2 = di * di;
        ushort4 o;
        o.x = f2bf(di * aA.x + d2 * sq.x); o.y = f2bf(di * aA.y + d2 * sq.y);
        o.z = f2bf(di * aA.z + d2 * sq.z); o.w = f2bf(di * aA.w + d2 * sq.w);
        *(ushort4*)&agg[(size_t)node * 128 + 4 * c] = o;
    } else if (grp == 1) {
        float rn = 1.0f / fmaxf((float)cn, 1.0f);
        ushort4 o;
        o.x = f2bf(aB.x * rn); o.y = f2bf(aB.y * rn);
        o.z = f2bf(aB.z * rn); o.w = f2bf(aB.w * rn);
        *(ushort4*)&agg[(size_t)node * 128 + 64 + 4 * c] = o;
    }
}

__global__ void k_gather2(const unsigned short* __restrict__ gs, const int* __restrict__ csr,
                          const int* __restrict__ offs, const int* __restrict__ cnt,
                          const float* __restrict__ dinv,
                          unsigned short* __restrict__ agg, int N) {
    int lane = threadIdx.x & 63;
    int wave = threadIdx.x >> 6;
    int node = blockIdx.x * 4 + wave;
    if (node >= N) return;
    int c = lane & 15, grp = lane >> 4;

    int st = offs[node];
    int cn = cnt[node];
    float di = dinv[node];

    float4 aC = {0.f, 0.f, 0.f, 0.f}, aD = {0.f, 0.f, 0.f, 0.f};
    for (int e = 0; e < cn; e += 8) {
        int i0 = e + grp, i1 = e + 4 + grp;
        float m0 = (i0 < cn) ? 1.f : 0.f;
        float m1 = (i1 < cn) ? 1.f : 0.f;
        int s0 = csr[st + (i0 < cn ? i0 : cn - 1)];
        int s1 = csr[st + (i1 < cn ? i1 : cn - 1)];
        float w0 = m0 * dinv[s0];
        float w1 = m1 * dinv[s1];
        const unsigned short* p0 = gs + (size_t)s0 * 128 + 4 * c;
        const unsigned short* p1 = gs + (size_t)s1 * 128 + 4 * c;
        ushort4 g0u = *(const ushort4*)p0;
        ushort4 g1u = *(const ushort4*)p1;
        ushort4 t0u = *(const ushort4*)(p0 + 64);
        ushort4 t1u = *(const ushort4*)(p1 + 64);
        aC.x += w0 * bf2f(g0u.x) + w1 * bf2f(g1u.x);
        aC.y += w0 * bf2f(g0u.y) + w1 * bf2f(g1u.y);
        aC.z += w0 * bf2f(g0u.z) + w1 * bf2f(g1u.z);
        aC.w += w0 * bf2f(g0u.w) + w1 * bf2f(g1u.w);
        aD.x += m0 * bf2f(t0u.x) + m1 * bf2f(t1u.x);
        aD.y += m0 * bf2f(t0u.y) + m1 * bf2f(t1u.y);
        aD.z += m0 * bf2f(t0u.z) + m1 * bf2f(t1u.z);
        aD.w += m0 * bf2f(t0u.w) + m1 * bf2f(t1u.w);
    }
    xor_reduce8(aC, aD);

    if (grp == 0) {
        ushort4 su = *(const ushort4*)&gs[(size_t)node * 128 + 4 * c];
        float d2 = di * di;
        ushort4 o;
        o.x = f2bf(di * aC.x + d2 * bf2f(su.x));
        o.y = f2bf(di * aC.y + d2 * bf2f(su.y));
        o.z = f2bf(di * aC.z + d2 * bf2f(su.z));
        o.w = f2bf(di * aC.w + d2 * bf2f(su.w));
        *(ushort4*)&agg[(size_t)node * 128 + 4 * c] = o;
    } else if (grp == 1) {
        float rn = 1.0f / fmaxf((float)cn, 1.0f);
        ushort4 o;
        o.x = f2bf(aD.x * rn); o.y = f2bf(aD.y * rn);
        o.z = f2bf(aD.z * rn); o.w = f2bf(aD.w * rn);
        *(ushort4*)&agg[(size_t)node * 128 + 64 + 4 * c] = o;
    }
}

// Layer-1 GEMMs via MFMA. use_xb selects bf16 or fp32 x source (uniform).
__launch_bounds__(512, 1)
__global__ void k_gemm1(const unsigned short* __restrict__ agg,
                        const unsigned short* __restrict__ xb,
                        const float* __restrict__ xf, int use_xb,
                        const float* __restrict__ W1, const float* __restrict__ b1,
                        const float* __restrict__ Wl1, const float* __restrict__ bl1,
                        const float* __restrict__ Wr1,
                        unsigned short* __restrict__ buf1, int N) {
    alignas(16) __shared__ unsigned short sW[3][4096];
    int t = threadIdx.x;
    for (int i = t; i < 1536; i += 512) {
        int m = i >> 9;
        int rem = i & 511;
        int f = rem >> 6;
        int L = rem & 63;
        int kb = (f >> 2) * 32 + (L >> 4) * 8;
        int o = (f & 3) * 16 + (L & 15);
        const float* Wsrc = (m == 0) ? W1 : (m == 1) ? Wl1 : Wr1;
        unsigned short* dst = &sW[m][f * 512 + L * 8];
        #pragma unroll
        for (int j = 0; j < 8; ++j) dst[j] = f2bf(Wsrc[(kb + j) * 64 + o]);
    }
    __syncthreads();

    int lane = t & 63;
    int wave = t >> 6;
    int quad = lane >> 4;
    int n16 = lane & 15;
    int base = blockIdx.x * 128 + wave * 16;
    if (base >= N) return;

    int nm = base + n16;
    if (nm >= N) nm = N - 1;
    const unsigned short* ar = agg + (size_t)nm * 128;

    {
        short8 a0 = *(const short8*)(ar + quad * 8);
        short8 a1 = *(const short8*)(ar + 32 + quad * 8);
        floatx4 g0 = {0.f, 0.f, 0.f, 0.f}, g1 = g0, g2 = g0, g3 = g0;
        g0 = __builtin_amdgcn_mfma_f32_16x16x32_bf16(a0, *(const short8*)&sW[0][0 * 512 + lane * 8], g0, 0, 0, 0);
        g0 = __builtin_amdgcn_mfma_f32_16x16x32_bf16(a1, *(const short8*)&sW[0][4 * 512 + lane * 8], g0, 0, 0, 0);
        g1 = __builtin_amdgcn_mfma_f32_16x16x32_bf16(a0, *(const short8*)&sW[0][1 * 512 + lane * 8], g1, 0, 0, 0);
        g1 = __builtin_amdgcn_mfma_f32_16x16x32_bf16(a1, *(const short8*)&sW[0][5 * 512 + lane * 8], g1, 0, 0, 0);
        g2 = __builtin_amdgcn_mfma_f32_16x16x32_bf16(a0, *(const short8*)&sW[0][2 * 512 + lane * 8], g2, 0, 0, 0);
        g2 = __builtin_amdgcn_mfma_f32_16x16x32_bf16(a1, *(const short8*)&sW[0][6 * 512 + lane * 8], g2, 0, 0, 0);
        g3 = __builtin_amdgcn_mfma_f32_16x16x32_bf16(a0, *(const short8*)&sW[0][3 * 512 + lane * 8], g3, 0, 0, 0);
        g3 = __builtin_amdgcn_mfma_f32_16x16x32_bf16(a1, *(const short8*)&sW[0][7 * 512 + lane * 8], g3, 0, 0, 0);
        floatx4 gt[4] = {g0, g1, g2, g3};
        #pragma unroll
        for (int nt = 0; nt < 4; ++nt) {
            float bg = b1[nt * 16 + n16];
            #pragma unroll
            for (int r = 0; r < 4; ++r) {
                int node = base + quad * 4 + r;
                if (node < N)
                    buf1[(size_t)node * 128 + nt * 16 + n16] = f2bf(fmaxf(gt[nt][r] + bg, 0.f));
            }
        }
    }

    {
        short8 a0 = *(const short8*)(ar + 64 + quad * 8);
        short8 a1 = *(const short8*)(ar + 96 + quad * 8);
        short8 ax0, ax1;
        if (use_xb) {
            ax0 = *(const short8*)&xb[(size_t)nm * 64 + quad * 8];
            ax1 = *(const short8*)&xb[(size_t)nm * 64 + 32 + quad * 8];
        } else {
            float4 xq0 = *(const float4*)&xf[(size_t)nm * 64 + quad * 8];
            float4 xq1 = *(const float4*)&xf[(size_t)nm * 64 + quad * 8 + 4];
            float4 xq2 = *(const float4*)&xf[(size_t)nm * 64 + 32 + quad * 8];
            float4 xq3 = *(const float4*)&xf[(size_t)nm * 64 + 32 + quad * 8 + 4];
            ax0[0] = (short)f2bf(xq0.x); ax0[1] = (short)f2bf(xq0.y);
            ax0[2] = (short)f2bf(xq0.z); ax0[3] = (short)f2bf(xq0.w);
            ax0[4] = (short)f2bf(xq1.x); ax0[5] = (short)f2bf(xq1.y);
            ax0[6] = (short)f2bf(xq1.z); ax0[7] = (short)f2bf(xq1.w);
            ax1[0] = (short)f2bf(xq2.x); ax1[1] = (short)f2bf(xq2.y);
            ax1[2] = (short)f2bf(xq2.z); ax1[3] = (short)f2bf(xq2.w);
            ax1[4] = (short)f2bf(xq3.x); ax1[5] = (short)f2bf(xq3.y);
            ax1[6] = (short)f2bf(xq3.z); ax1[7] = (short)f2bf(xq3.w);
        }

        floatx4 s0 = {0.f, 0.f, 0.f, 0.f}, s1 = s0, s2 = s0, s3 = s0;
        s0 = __builtin_amdgcn_mfma_f32_16x16x32_bf16(a0, *(const short8*)&sW[1][0 * 512 + lane * 8], s0, 0, 0, 0);
        s0 = __builtin_amdgcn_mfma_f32_16x16x32_bf16(a1, *(const short8*)&sW[1][4 * 512 + lane * 8], s0, 0, 0, 0);
        s0 = __builtin_amdgcn_mfma_f32_16x16x32_bf16(ax0, *(const short8*)&sW[2][0 * 512 + lane * 8], s0, 0, 0, 0);
        s0 = __builtin_amdgcn_mfma_f32_16x16x32_bf16(ax1, *(const short8*)&sW[2][4 * 512 + lane * 8], s0, 0, 0, 0);
        s1 = __builtin_amdgcn_mfma_f32_16x16x32_bf16(a0, *(const short8*)&sW[1][1 * 512 + lane * 8], s1, 0, 0, 0);
        s1 = __builtin_amdgcn_mfma_f32_16x16x32_bf16(a1, *(const short8*)&sW[1][5 * 512 + lane * 8], s1, 0, 0, 0);
        s1 = __builtin_amdgcn_mfma_f32_16x16x32_bf16(ax0, *(const short8*)&sW[2][1 * 512 + lane * 8], s1, 0, 0, 0);
        s1 = __builtin_amdgcn_mfma_f32_16x16x32_bf16(ax1, *(const short8*)&sW[2][5 * 512 + lane * 8], s1, 0, 0, 0);
        s2 = __builtin_amdgcn_mfma_f32_16x16x32_bf16(a0, *(const short8*)&sW[1][2 * 512 + lane * 8], s2, 0, 0, 0);
        s2 = __builtin_amdgcn_mfma_f32_16x16x32_bf16(a1, *(const short8*)&sW[1][6 * 512 + lane * 8], s2, 0, 0, 0);
        s2 = __builtin_amdgcn_mfma_f32_16x16x32_bf16(ax0, *(const short8*)&sW[2][2 * 512 + lane * 8], s2, 0, 0, 0);
        s2 = __builtin_amdgcn_mfma_f32_16x16x32_bf16(ax1, *(const short8*)&sW[2][6 * 512 + lane * 8], s2, 0, 0, 0);
        s3 = __builtin_amdgcn_mfma_f32_16x16x32_bf16(a0, *(const short8*)&sW[1][3 * 512 + lane * 8], s3, 0, 0, 0);
        s3 = __builtin_amdgcn_mfma_f32_16x16x32_bf16(a1, *(const short8*)&sW[1][7 * 512 + lane * 8], s3, 0, 0, 0);
        s3 = __builtin_amdgcn_mfma_f32_16x16x32_bf16(ax0, *(const short8*)&sW[2][3 * 512 + lane * 8], s3, 0, 0, 0);
        s3 = __builtin_amdgcn_mfma_f32_16x16x32_bf16(ax1, *(const short8*)&sW[2][7 * 512 + lane * 8], s3, 0, 0, 0);
        floatx4 stl[4] = {s0, s1, s2, s3};
        #pragma unroll
        for (int nt = 0; nt < 4; ++nt) {
            float bs = bl1[nt * 16 + n16];
            #pragma unroll
            for (int r = 0; r < 4; ++r) {
                int node = base + quad * 4 + r;
                if (node < N)
                    buf1[(size_t)node * 128 + 64 + nt * 16 + n16] = f2bf(fmaxf(stl[nt][r] + bs, 0.f));
            }
        }
    }
}

// Layer-2 GEMMs + LN + concat-proj via MFMA (proven in R8).
__launch_bounds__(512, 1)
__global__ void k_gemm2(const unsigned short* __restrict__ agg,
                        const unsigned short* __restrict__ buf1,
                        const float* __restrict__ W2, const float* __restrict__ b2,
                        const float* __restrict__ Wl2, const float* __restrict__ bl2,
                        const float* __restrict__ Wr2,
                        const float* __restrict__ lngG, const float* __restrict__ lnbG,
                        const float* __restrict__ lngS, const float* __restrict__ lnbS,
                        const float* __restrict__ Pw, const float* __restrict__ Pb,
                        float* __restrict__ out, int N) {
    alignas(16) __shared__ unsigned short sW[3][4096];
    alignas(16) __shared__ unsigned short sP[8192];
    alignas(16) __shared__ unsigned short sT[8][16 * 132];
    int t = threadIdx.x;
    for (int i = t; i < 1536; i += 512) {
        int m = i >> 9;
        int rem = i & 511;
        int f = rem >> 6;
        int L = rem & 63;
        int kb = (f >> 2) * 32 + (L >> 4) * 8;
        int o = (f & 3) * 16 + (L & 15);
        const float* Wsrc = (m == 0) ? W2 : (m == 1) ? Wl2 : Wr2;
        unsigned short* dst = &sW[m][f * 512 + L * 8];
        #pragma unroll
        for (int j = 0; j < 8; ++j) dst[j] = f2bf(Wsrc[(kb + j) * 64 + o]);
    }
    for (int i = t; i < 1024; i += 512) {
        int f = i >> 6;
        int L = i & 63;
        int kb = (f >> 2) * 32 + (L >> 4) * 8;
        int o = (f & 3) * 16 + (L & 15);
        unsigned short* dst = &sP[f * 512 + L * 8];
        #pragma unroll
        for (int j = 0; j < 8; ++j) dst[j] = f2bf(Pw[(kb + j) * 64 + o]);
    }
    __syncthreads();

    int lane = t & 63;
    int wave = t >> 6;
    int quad = lane >> 4;
    int n16 = lane & 15;
    int base = blockIdx.x * 128 + wave * 16;
    if (base >= N) return;
    int nm = base + n16;
    if (nm >= N) nm = N - 1;
    const unsigned short* ar = agg + (size_t)nm * 128;
    const unsigned short* br = buf1 + (size_t)nm * 128;
    unsigned short* tw = &sT[wave][0];

    {
        short8 a0 = *(const short8*)(ar + quad * 8);
        short8 a1 = *(const short8*)(ar + 32 + quad * 8);
        floatx4 c0 = {0.f, 0.f, 0.f, 0.f}, c1 = c0, c2 = c0, c3 = c0;
        c0 = __builtin_amdgcn_mfma_f32_16x16x32_bf16(a0, *(const short8*)&sW[0][0 * 512 + lane * 8], c0, 0, 0, 0);
        c0 = __builtin_amdgcn_mfma_f32_16x16x32_bf16(a1, *(const short8*)&sW[0][4 * 512 + lane * 8], c0, 0, 0, 0);
        c1 = __builtin_amdgcn_mfma_f32_16x16x32_bf16(a0, *(const short8*)&sW[0][1 * 512 + lane * 8], c1, 0, 0, 0);
        c1 = __builtin_amdgcn_mfma_f32_16x16x32_bf16(a1, *(const short8*)&sW[0][5 * 512 + lane * 8], c1, 0, 0, 0);
        c2 = __builtin_amdgcn_mfma_f32_16x16x32_bf16(a0, *(const short8*)&sW[0][2 * 512 + lane * 8], c2, 0, 0, 0);
        c2 = __builtin_amdgcn_mfma_f32_16x16x32_bf16(a1, *(const short8*)&sW[0][6 * 512 + lane * 8], c2, 0, 0, 0);
        c3 = __builtin_amdgcn_mfma_f32_16x16x32_bf16(a0, *(const short8*)&sW[0][3 * 512 + lane * 8], c3, 0, 0, 0);
        c3 = __builtin_amdgcn_mfma_f32_16x16x32_bf16(a1, *(const short8*)&sW[0][7 * 512 + lane * 8], c3, 0, 0, 0);

        float bv0 = b2[n16], bv1 = b2[16 + n16], bv2 = b2[32 + n16], bv3 = b2[48 + n16];
        float gv0 = lngG[n16], gv1 = lngG[16 + n16], gv2 = lngG[32 + n16], gv3 = lngG[48 + n16];
        float ev0 = lnbG[n16], ev1 = lnbG[16 + n16], ev2 = lnbG[32 + n16], ev3 = lnbG[48 + n16];
        #pragma unroll
        for (int r = 0; r < 4; ++r) {
            float z0 = c0[r] + bv0, z1 = c1[r] + bv1, z2 = c2[r] + bv2, z3 = c3[r] + bv3;
            float s = red16(z0 + z1 + z2 + z3);
            float q = red16(z0 * z0 + z1 * z1 + z2 * z2 + z3 * z3);
            float mu = s * (1.0f / 64.0f);
            float var = fmaxf(q * (1.0f / 64.0f) - mu * mu, 0.0f);
            float rs = rsqrtf(var + 1e-5f);
            unsigned short* row = tw + (quad * 4 + r) * 132;
            row[n16]      = f2bf((z0 - mu) * rs * gv0 + ev0);
            row[16 + n16] = f2bf((z1 - mu) * rs * gv1 + ev1);
            row[32 + n16] = f2bf((z2 - mu) * rs * gv2 + ev2);
            row[48 + n16] = f2bf((z3 - mu) * rs * gv3 + ev3);
        }
    }

    {
        short8 a0 = *(const short8*)(ar + 64 + quad * 8);
        short8 a1 = *(const short8*)(ar + 96 + quad * 8);
        short8 v0 = *(const short8*)(br + 64 + quad * 8);
        short8 v1 = *(const short8*)(br + 96 + quad * 8);
        floatx4 c0 = {0.f, 0.f, 0.f, 0.f}, c1 = c0, c2 = c0, c3 = c0;
        c0 = __builtin_amdgcn_mfma_f32_16x16x32_bf16(a0, *(const short8*)&sW[1][0 * 512 + lane * 8], c0, 0, 0, 0);
        c0 = __builtin_amdgcn_mfma_f32_16x16x32_bf16(a1, *(const short8*)&sW[1][4 * 512 + lane * 8], c0, 0, 0, 0);
        c0 = __builtin_amdgcn_mfma_f32_16x16x32_bf16(v0, *(const short8*)&sW[2][0 * 512 + lane * 8], c0, 0, 0, 0);
        c0 = __builtin_amdgcn_mfma_f32_16x16x32_bf16(v1, *(const short8*)&sW[2][4 * 512 + lane * 8], c0, 0, 0, 0);
        c1 = __builtin_amdgcn_mfma_f32_16x16x32_bf16(a0, *(const short8*)&sW[1][1 * 512 + lane * 8], c1, 0, 0, 0);
        c1 = __builtin_amdgcn_mfma_f32_16x16x32_bf16(a1, *(const short8*)&sW[1][5 * 512 + lane * 8], c1, 0, 0, 0);
        c1 = __builtin_amdgcn_mfma_f32_16x16x32_bf16(v0, *(const short8*)&sW[2][1 * 512 + lane * 8], c1, 0, 0, 0);
        c1 = __builtin_amdgcn_mfma_f32_16x16x32_bf16(v1, *(const short8*)&sW[2][5 * 512 + lane * 8], c1, 0, 0, 0);
        c2 = __builtin_amdgcn_mfma_f32_16x16x32_bf16(a0, *(const short8*)&sW[1][2 * 512 + lane * 8], c2, 0, 0, 0);
        c2 = __builtin_amdgcn_mfma_f32_16x16x32_bf16(a1, *(const short8*)&sW[1][6 * 512 + lane * 8], c2, 0, 0, 0);
        c2 = __builtin_amdgcn_mfma_f32_16x16x32_bf16(v0, *(const short8*)&sW[2][2 * 512 + lane * 8], c2, 0, 0, 0);
        c2 = __builtin_amdgcn_mfma_f32_16x16x32_bf16(v1, *(const short8*)&sW[2][6 * 512 + lane * 8], c2, 0, 0, 0);
        c3 = __builtin_amdgcn_mfma_f32_16x16x32_bf16(a0, *(const short8*)&sW[1][3 * 512 + lane * 8], c3, 0, 0, 0);
        c3 = __builtin_amdgcn_mfma_f32_16x16x32_bf16(a1, *(const short8*)&sW[1][7 * 512 + lane * 8], c3, 0, 0, 0);
        c3 = __builtin_amdgcn_mfma_f32_16x16x32_bf16(v0, *(const short8*)&sW[2][3 * 512 + lane * 8], c3, 0, 0, 0);
        c3 = __builtin_amdgcn_mfma_f32_16x16x32_bf16(v1, *(const short8*)&sW[2][7 * 512 + lane * 8], c3, 0, 0, 0);

        float bv0 = bl2[n16], bv1 = bl2[16 + n16], bv2 = bl2[32 + n16], bv3 = bl2[48 + n16];
        float gv0 = lngS[n16], gv1 = lngS[16 + n16], gv2 = lngS[32 + n16], gv3 = lngS[48 + n16];
        float ev0 = lnbS[n16], ev1 = lnbS[16 + n16], ev2 = lnbS[32 + n16], ev3 = lnbS[48 + n16];
        #pragma unroll
        for (int r = 0; r < 4; ++r) {
            float z0 = c0[r] + bv0, z1 = c1[r] + bv1, z2 = c2[r] + bv2, z3 = c3[r] + bv3;
            float s = red16(z0 + z1 + z2 + z3);
            float q = red16(z0 * z0 + z1 * z1 + z2 * z2 + z3 * z3);
            float mu = s * (1.0f / 64.0f);
            float var = fmaxf(q * (1.0f / 64.0f) - mu * mu, 0.0f);
            float rs = rsqrtf(var + 1e-5f);
            unsigned short* row = tw + (quad * 4 + r) * 132 + 64;
            row[n16]      = f2bf((z0 - mu) * rs * gv0 + ev0);
            row[16 + n16] = f2bf((z1 - mu) * rs * gv1 + ev1);
            row[32 + n16] = f2bf((z2 - mu) * rs * gv2 + ev2);
            row[48 + n16] = f2bf((z3 - mu) * rs * gv3 + ev3);
        }
    }

    floatx4 o0 = {0.f, 0.f, 0.f, 0.f}, o1 = o0, o2 = o0, o3 = o0;
    #pragma unroll
    for (int ks = 0; ks < 4; ++ks) {
        const unsigned short* ap = tw + n16 * 132 + ks * 32 + quad * 8;
        short4v lo = *(const short4v*)ap;
        short4v hi = *(const short4v*)(ap + 4);
        short8 af;
        af[0] = lo[0]; af[1] = lo[1]; af[2] = lo[2]; af[3] = lo[3];
        af[4] = hi[0]; af[5] = hi[1]; af[6] = hi[2]; af[7] = hi[3];
        o0 = __builtin_amdgcn_mfma_f32_16x16x32_bf16(af, *(const short8*)&sP[(ks * 4 + 0) * 512 + lane * 8], o0, 0, 0, 0);
        o1 = __builtin_amdgcn_mfma_f32_16x16x32_bf16(af, *(const short8*)&sP[(ks * 4 + 1) * 512 + lane * 8], o1, 0, 0, 0);
        o2 = __builtin_amdgcn_mfma_f32_16x16x32_bf16(af, *(const short8*)&sP[(ks * 4 + 2) * 512 + lane * 8], o2, 0, 0, 0);
        o3 = __builtin_amdgcn_mfma_f32_16x16x32_bf16(af, *(const short8*)&sP[(ks * 4 + 3) * 512 + lane * 8], o3, 0, 0, 0);
    }
    float p0 = Pb[n16], p1 = Pb[16 + n16], p2 = Pb[32 + n16], p3 = Pb[48 + n16];
    floatx4 ot[4] = {o0, o1, o2, o3};
    float pv[4] = {p0, p1, p2, p3};
    #pragma unroll
    for (int nt = 0; nt < 4; ++nt) {
        #pragma unroll
        for (int r = 0; r < 4; ++r) {
            int node = base + quad * 4 + r;
            if (node < N) out[(size_t)node * 64 + nt * 16 + n16] = ot[nt][r] + pv[nt];
        }
    }
}

extern "C" void kernel_launch(void* const* d_in, const int* in_sizes, int n_in,
                              void* d_out, int out_size, void* d_ws, size_t ws_size,
                              hipStream_t stream) {
    const float* x        = (const float*)d_in[0];
    const int*   ei       = (const int*)d_in[1];
    const float* gcn_w1   = (const float*)d_in[2];
    const float* gcn_b1   = (const float*)d_in[3];
    const float* gcn_w2   = (const float*)d_in[4];
    const float* gcn_b2   = (const float*)d_in[5];
    const float* sage_wl1 = (const float*)d_in[6];
    const float* sage_bl1 = (const float*)d_in[7];
    const float* sage_wr1 = (const float*)d_in[8];
    const float* sage_wl2 = (const float*)d_in[9];
    const float* sage_bl2 = (const float*)d_in[10];
    const float* sage_wr2 = (const float*)d_in[11];
    const float* gcn_ln_g = (const float*)d_in[12];
    const float* gcn_ln_b = (const float*)d_in[13];
    const float* sage_ln_g = (const float*)d_in[14];
    const float* sage_ln_b = (const float*)d_in[15];
    const float* proj_w   = (const float*)d_in[16];
    const float* proj_b   = (const float*)d_in[17];
    float* out = (float*)d_out;

    const int N = in_sizes[0] / 64;
    const int E = in_sizes[1] / 2;
    const int B = (N + SCAN_CHUNK - 1) / SCAN_CHUNK;

    char* w = (char*)d_ws;
    size_t off = 0;
    auto alloc = [&](size_t bytes) -> void* {
        void* p = w + off;
        off = (off + bytes + 255) & ~(size_t)255;
        return p;
    };
    int*            cnt       = (int*)alloc((size_t)N * 4);
    int*            offs      = (int*)alloc((size_t)(N + 1) * 4);
    float*          dinv      = (float*)alloc((size_t)N * 4);
    int*            blockSums = (int*)alloc((size_t)(B + 1) * 4);
    int*            csr       = (int*)alloc((size_t)(E + N + 64) * 4);
    unsigned short* agg       = (unsigned short*)alloc((size_t)N * 128 * 2);  // also aliases rank (dead before gather1)
    unsigned short* buf1      = (unsigned short*)alloc((size_t)N * 128 * 2);
    size_t off_nonew = off;
    unsigned int*   pk        = (unsigned int*)alloc((size_t)(E + N + 64) * 4);
    unsigned short* xb        = (unsigned short*)alloc((size_t)N * 64 * 2);
    int use_new = (off <= ws_size) ? 1 : 0;
    if (!use_new) off = off_nonew;
    int* rank = (int*)agg;  // E*4 = 5MB <= 25.6MB agg region
    (void)n_in; (void)out_size;

    hipMemsetAsync(cnt, 0, (size_t)N * 4, stream);

    int e4Blocks = ((E + 3) / 4 + 255) / 256;
    k_count<<<e4Blocks, 256, 0, stream>>>(ei, E, cnt, rank);
    k_scan_reduce<<<B, 256, 0, stream>>>(cnt, N, blockSums);
    k_scan_spine<<<1, 64, 0, stream>>>(blockSums, B);
    k_scan_write<<<B, 256, 0, stream>>>(cnt, N, blockSums, offs, dinv);
    k_fill<<<e4Blocks, 256, 0, stream>>>(ei, E, offs, rank, dinv, csr, pk, use_new);

    if (use_new) {
        k_self<<<(N + 255) / 256, 256, 0, stream>>>(offs, cnt, dinv, csr, pk, N);
        int xBlocks = ((N * 64 + 7) / 8 + 255) / 256;
        k_xtobf16<<<xBlocks, 256, 0, stream>>>(x, xb, N * 64);
        k_gatherM<64><<<(N + 31) / 32, 128, 0, stream>>>(xb, csr, pk, offs, cnt, agg, N);
        k_gemm1<<<(N + 127) / 128, 512, 0, stream>>>(agg, xb, x, 1, gcn_w1, gcn_b1,
                                                     sage_wl1, sage_bl1, sage_wr1, buf1, N);
        k_gatherM<128><<<(N + 31) / 32, 128, 0, stream>>>(buf1, csr, pk, offs, cnt, agg, N);
    } else {
        k_gather1_f32<<<(N + 3) / 4, 256, 0, stream>>>(x, csr, offs, cnt, dinv, agg, N);
        k_gemm1<<<(N + 127) / 128, 512, 0, stream>>>(agg, xb, x, 0, gcn_w1, gcn_b1,
                                                     sage_wl1, sage_bl1, sage_wr1, buf1, N);
        k_gather2<<<(N + 3) / 4, 256, 0, stream>>>(buf1, csr, offs, cnt, dinv, agg, N);
    }
    k_gemm2<<<(N + 127) / 128, 512, 0, stream>>>(agg, buf1, gcn_w2, gcn_b2,
                                                 sage_wl2, sage_bl2, sage_wr2,
                                                 gcn_ln_g, gcn_ln_b, sage_ln_g, sage_ln_b,
                                                 proj_w, proj_b, out, N);
}

// Round 5
// 334.417 us; speedup vs baseline: 1.0820x; 1.0820x over previous
//
#include <hip/hip_runtime.h>

// N=100000 nodes, E=1250000 edges, all dims 64.
// R14: revert to R10's proven serial gather structure (53.9us) — R11/R13
// pipelining attempts all regressed (VGPR/occupancy cost + gll serialization
// with scattered sources). Keep only the individually-proven wins:
//  (1) conflict-free staging map (R11): lane L ds_writes byte p*1024+16L,
//      bijection of the subtiled LDS image -> no 8-way write conflicts.
//  (2) hoisted resident meta (R13): csr+pk for <=256-edge range in 8 VGPRs,
//      no per-chunk meta loads (rare dynamic path beyond 256).
//  (3) self-loop materialized in CSR (R11): pk bit20 = SAGE-exclude.
// Plus launch merges: xtobf16 fused into k_count, k_self fused into k_fill.

#define SCAN_CHUNK 2048

typedef __attribute__((ext_vector_type(8))) short short8;   // 8 bf16 = 4 VGPRs
typedef __attribute__((ext_vector_type(4))) short short4v;  // 4 bf16 = 2 VGPRs
typedef __attribute__((ext_vector_type(4))) float floatx4;  // MFMA C/D

__device__ __forceinline__ unsigned short f2bf(float f) {
    unsigned int u = __float_as_uint(f);
    unsigned int r = u + 0x7FFFu + ((u >> 16) & 1u);  // round-to-nearest-even
    return (unsigned short)(r >> 16);
}
__device__ __forceinline__ float bf2f(unsigned short h) {
    return __uint_as_float(((unsigned int)h) << 16);
}

__device__ __forceinline__ unsigned lds_addr(const void* p) {
    return (unsigned)(unsigned long long)(__attribute__((address_space(3))) const char*)p;
}

__device__ __forceinline__ short8 cat44(short4v lo, short4v hi) {
    short8 r;
    r[0] = lo[0]; r[1] = lo[1]; r[2] = lo[2]; r[3] = lo[3];
    r[4] = hi[0]; r[5] = hi[1]; r[6] = hi[2]; r[7] = hi[3];
    return r;
}

// Read 4 B-frags (col-tiles CTB..CTB+3) for this lane's k-group via HW transpose.
// LDS holds 32xROWSH bf16 tile subtiled [k/4][f/16][4][16]; subtile s at byte s*128.
// a0 = wb_base + (q*2*NF)*128 + (lane&15)*8.
template<int NF, int CTB>
__device__ __forceinline__ void tr_read4(unsigned a0, short8 bf[4]) {
    short4v l0, h0, l1, h1, l2, h2, l3, h3;
    asm volatile(
        "ds_read_b64_tr_b16 %0, %8 offset:%9\n\t"
        "ds_read_b64_tr_b16 %1, %8 offset:%10\n\t"
        "ds_read_b64_tr_b16 %2, %8 offset:%11\n\t"
        "ds_read_b64_tr_b16 %3, %8 offset:%12\n\t"
        "ds_read_b64_tr_b16 %4, %8 offset:%13\n\t"
        "ds_read_b64_tr_b16 %5, %8 offset:%14\n\t"
        "ds_read_b64_tr_b16 %6, %8 offset:%15\n\t"
        "ds_read_b64_tr_b16 %7, %8 offset:%16\n\t"
        "s_waitcnt lgkmcnt(0)"
        : "=&v"(l0), "=&v"(h0), "=&v"(l1), "=&v"(h1),
          "=&v"(l2), "=&v"(h2), "=&v"(l3), "=&v"(h3)
        : "v"(a0),
          "i"((0 * NF + CTB + 0) * 128), "i"((1 * NF + CTB + 0) * 128),
          "i"((0 * NF + CTB + 1) * 128), "i"((1 * NF + CTB + 1) * 128),
          "i"((0 * NF + CTB + 2) * 128), "i"((1 * NF + CTB + 2) * 128),
          "i"((0 * NF + CTB + 3) * 128), "i"((1 * NF + CTB + 3) * 128)
        : "memory");
    bf[0] = cat44(l0, h0);
    bf[1] = cat44(l1, h1);
    bf[2] = cat44(l2, h2);
    bf[3] = cat44(l3, h3);
}

// count + record per-edge rank; fused x->bf16 conversion on spare threads
__global__ void k_count(const int* __restrict__ ei, int E, int* __restrict__ cnt,
                        int* __restrict__ rank,
                        const float* __restrict__ x, unsigned short* __restrict__ xb,
                        int xtotal, int do_x) {
    int i = blockIdx.x * blockDim.x + threadIdx.x;
    int e = i * 4;
    if (e + 4 <= E) {
        int4 d = *(const int4*)&ei[E + e];
        int4 r;
        r.x = atomicAdd(&cnt[d.x], 1);
        r.y = atomicAdd(&cnt[d.y], 1);
        r.z = atomicAdd(&cnt[d.z], 1);
        r.w = atomicAdd(&cnt[d.w], 1);
        *(int4*)&rank[e] = r;
    } else if (e < E) {
        for (int j = e; j < E; ++j) rank[j] = atomicAdd(&cnt[ei[E + j]], 1);
    }
    if (do_x) {
        int xe = i * 8;
        if (xe + 8 <= xtotal) {
            float4 a = *(const float4*)&x[xe];
            float4 b = *(const float4*)&x[xe + 4];
            short8 o;
            o[0] = (short)f2bf(a.x); o[1] = (short)f2bf(a.y);
            o[2] = (short)f2bf(a.z); o[3] = (short)f2bf(a.w);
            o[4] = (short)f2bf(b.x); o[5] = (short)f2bf(b.y);
            o[6] = (short)f2bf(b.z); o[7] = (short)f2bf(b.w);
            *(short8*)&xb[xe] = o;
        } else if (xe < xtotal) {
            for (int j = xe; j < xtotal; ++j) xb[j] = f2bf(x[j]);
        }
    }
}

// scan over (cnt[i] + 1): one self-loop slot per node appended to its edge range
__global__ void k_scan_reduce(const int* __restrict__ cnt, int N, int* __restrict__ blockSums) {
    __shared__ int lds[256];
    int base = blockIdx.x * SCAN_CHUNK;
    int t = threadIdx.x;
    int s = 0;
    for (int j = 0; j < 8; ++j) {
        int idx = base + t * 8 + j;
        if (idx < N) s += cnt[idx] + 1;
    }
    lds[t] = s;
    __syncthreads();
    for (int d = 128; d > 0; d >>= 1) {
        if (t < d) lds[t] += lds[t + d];
        __syncthreads();
    }
    if (t == 0) blockSums[blockIdx.x] = lds[0];
}

__global__ void k_scan_spine(int* __restrict__ blockSums, int B) {
    if (threadIdx.x == 0 && blockIdx.x == 0) {
        int run = 0;
        for (int b = 0; b < B; ++b) { int v = blockSums[b]; blockSums[b] = run; run += v; }
    }
}

__global__ void k_scan_write(const int* __restrict__ cnt, int N,
                             const int* __restrict__ blockSums,
                             int* __restrict__ offs, float* __restrict__ dinv) {
    __shared__ int lds[256];
    int base = blockIdx.x * SCAN_CHUNK;
    int t = threadIdx.x;
    int v[8];
    int s = 0;
    for (int j = 0; j < 8; ++j) {
        int idx = base + t * 8 + j;
        v[j] = (idx < N) ? cnt[idx] : 0;
        s += (idx < N) ? v[j] + 1 : 0;
    }
    lds[t] = s;
    __syncthreads();
    for (int d = 1; d < 256; d <<= 1) {
        int x = (t >= d) ? lds[t - d] : 0;
        __syncthreads();
        lds[t] += x;
        __syncthreads();
    }
    int excl = (t == 0) ? 0 : lds[t - 1];
    int run = blockSums[blockIdx.x] + excl;
    for (int j = 0; j < 8; ++j) {
        int idx = base + t * 8 + j;
        if (idx < N) {
            offs[idx] = run;
            run += v[j] + 1;
            dinv[idx] = rsqrtf((float)v[j] + 1.0f);
            if (idx == N - 1) offs[N] = run;  // total incl. self slots
        }
    }
}

// atomic-free fill: pos = offs[dst] + rank[e]; emits pk = (dst&15)<<16 | bf16(ew);
// fused self-loop write (thread i also handles node i): weight di^2, bit20 set.
__global__ void k_fill(const int* __restrict__ ei, int E, const int* __restrict__ offs,
                       const int* __restrict__ rank, const int* __restrict__ cnt,
                       const float* __restrict__ dinv,
                       int* __restrict__ csr, unsigned int* __restrict__ pk,
                       int use_pk, int N) {
    int i = blockIdx.x * blockDim.x + threadIdx.x;
    int e = i * 4;
    if (e + 4 <= E) {
        int4 s = *(const int4*)&ei[e];
        int4 d = *(const int4*)&ei[E + e];
        int4 r = *(const int4*)&rank[e];
        int p0 = offs[d.x] + r.x, p1 = offs[d.y] + r.y;
        int p2 = offs[d.z] + r.z, p3 = offs[d.w] + r.w;
        csr[p0] = s.x; csr[p1] = s.y; csr[p2] = s.z; csr[p3] = s.w;
        if (use_pk) {
            pk[p0] = ((unsigned)(d.x & 15) << 16) | f2bf(dinv[s.x] * dinv[d.x]);
            pk[p1] = ((unsigned)(d.y & 15) << 16) | f2bf(dinv[s.y] * dinv[d.y]);
            pk[p2] = ((unsigned)(d.z & 15) << 16) | f2bf(dinv[s.z] * dinv[d.z]);
            pk[p3] = ((unsigned)(d.w & 15) << 16) | f2bf(dinv[s.w] * dinv[d.w]);
        }
    } else if (e < E) {
        for (int j = e; j < E; ++j) {
            int dd = ei[E + j];
            int p = offs[dd] + rank[j];
            csr[p] = ei[j];
            if (use_pk) pk[p] = ((unsigned)(dd & 15) << 16) | f2bf(dinv[ei[j]] * dinv[dd]);
        }
    }
    if (use_pk && i < N) {
        int pos = offs[i] + cnt[i];
        float di = dinv[i];
        csr[pos] = i;
        pk[pos] = ((unsigned)(i & 15) << 16) | (1u << 20) | f2bf(di * di);
    }
}

// ===================== MFMA SpMM gather (serial, proven R10 structure) ========
// One wave per 16 dst nodes; 4 waves/block; no barriers. Edges incl. self-loops
// contiguous in [offs[base], offs[base+16)). Per 32-edge chunk: reg-stage 32 src
// rows -> conflict-free ds_write (lane L -> byte p*1024+16L of subtiled image),
// A-frags from resident meta regs via shfl, tr_read + 8 MFMAs.
template<int ROWSH>
__launch_bounds__(256)
__global__ void k_gatherM(const unsigned short* __restrict__ feat,
                          const int* __restrict__ csr,
                          const unsigned int* __restrict__ pk,
                          const int* __restrict__ offs, const int* __restrict__ cnt,
                          unsigned short* __restrict__ agg, int N) {
    constexpr int NF = ROWSH / 16;      // f-subtiles per edge row (4 or 8)
    constexpr int LPR = ROWSH / 8;      // lanes per staged row
    constexpr int EPP = 64 / LPR;       // edges per staging pass
    constexpr int PASSES = 32 / EPP;    // passes per 32-edge chunk (4 or 8)

    __shared__ unsigned short sbuf[4][32 * ROWSH];

    const int lane = threadIdx.x & 63;
    const int wv = threadIdx.x >> 6;
    const int base = blockIdx.x * 64 + wv * 16;
    if (base >= N) return;

    const int q = lane >> 4;
    const int d16 = lane & 15;

    // conflict-free staging map: lane L holds the 16B that belongs at byte
    // p*1024 + 16L of the subtiled LDS image (bijection per 1024B pass block).
    const int parity = lane & 1;
    const int ei_low = (lane >> 1) & 3;
    const int sf_sub = (lane >> 3) & (NF - 1);
    const int ei_high = (NF == 8) ? 0 : (lane >> 5);
    const int eid = ei_high * 4 + ei_low;
    const int sf = sf_sub * 16 + parity * 8;

    const int elo = offs[base];
    const int ehi = offs[min(base + 16, N)];
    const int emax = ehi - 1;
    const int nch = (ehi - elo + 31) >> 5;

    // ---- resident meta: 4 windows of 64 edges (covers 8 chunks = 256 edges) ----
    int cM0, cM1, cM2, cM3;
    unsigned pM0, pM1, pM2, pM3;
    {
        int i0 = elo + lane;
        int i1 = i0 + 64, i2 = i0 + 128, i3 = i0 + 192;
        cM0 = csr[i0 <= emax ? i0 : emax];
        cM1 = csr[i1 <= emax ? i1 : emax];
        cM2 = csr[i2 <= emax ? i2 : emax];
        cM3 = csr[i3 <= emax ? i3 : emax];
        unsigned t0 = pk[i0 <= emax ? i0 : emax];
        unsigned t1 = pk[i1 <= emax ? i1 : emax];
        unsigned t2 = pk[i2 <= emax ? i2 : emax];
        unsigned t3 = pk[i3 <= emax ? i3 : emax];
        pM0 = (i0 < ehi) ? t0 : 0x00100000u;
        pM1 = (i1 < ehi) ? t1 : 0x00100000u;
        pM2 = (i2 < ehi) ? t2 : 0x00100000u;
        pM3 = (i3 < ehi) ? t3 : 0x00100000u;
    }

    floatx4 accg[4], accs[4];
#pragma unroll
    for (int i = 0; i < 4; ++i) {
        accg[i] = floatx4{0.f, 0.f, 0.f, 0.f};
        accs[i] = floatx4{0.f, 0.f, 0.f, 0.f};
    }

    unsigned short* wb = &sbuf[wv][0];
    const unsigned a0 = lds_addr(wb) + (unsigned)(q * 2 * NF) * 128u + (unsigned)d16 * 8u;

    for (int c = 0; c < nch; ++c) {
        // ---- meta for chunk c (resident regs; rare dynamic path >256 edges) ----
        int cv; unsigned pv; int wofs;
        int rc = c >> 1;
        if (rc < 4) {
            wofs = (c & 1) << 5;
            cv = (rc == 0) ? cM0 : (rc == 1) ? cM1 : (rc == 2) ? cM2 : cM3;
            pv = (rc == 0) ? pM0 : (rc == 1) ? pM1 : (rc == 2) ? pM2 : pM3;
        } else {
            int idx = elo + (c << 5) + lane;
            int idc = idx <= emax ? idx : emax;
            cv = csr[idc];
            unsigned t = pk[idc];
            pv = (idx < ehi) ? t : 0x00100000u;
            wofs = 0;
        }

        // ---- issue row loads (addresses from resident regs, no meta loads) ----
        short8 stg[PASSES];
#pragma unroll
        for (int p = 0; p < PASSES; ++p) {
            int src = __shfl(cv, wofs + p * EPP + eid, 64);
            stg[p] = *(const short8*)&feat[(size_t)src * ROWSH + sf];
        }

        // ---- A-frags (register-only; overlaps load latency) ----
        short8 aG, aS;
#pragma unroll
        for (int j = 0; j < 8; ++j) {
            unsigned u = (unsigned)__shfl((int)pv, wofs + q * 8 + j, 64);
            unsigned hi = u >> 16;
            bool match = (int)(hi & 15u) == d16;
            aG[j] = match ? (short)(u & 0xFFFFu) : (short)0;
            aS[j] = (match && !(hi & 16u)) ? (short)0x3F80 : (short)0;
        }

        // ---- conflict-free ds_write (compiler inserts vmcnt waits for stg) ----
#pragma unroll
        for (int p = 0; p < PASSES; ++p)
            *(short8*)&wb[p * 512 + lane * 8] = stg[p];
        asm volatile("s_waitcnt lgkmcnt(0)" ::: "memory");
        __builtin_amdgcn_sched_barrier(0);

        // ---- tr_read + MFMA ----
        short8 bG[4];
        tr_read4<NF, 0>(a0, bG);
#pragma unroll
        for (int ct = 0; ct < 4; ++ct)
            accg[ct] = __builtin_amdgcn_mfma_f32_16x16x32_bf16(aG, bG[ct], accg[ct], 0, 0, 0);
        if constexpr (NF == 8) {
            short8 bS[4];
            tr_read4<NF, 4>(a0, bS);
#pragma unroll
            for (int ct = 0; ct < 4; ++ct)
                accs[ct] = __builtin_amdgcn_mfma_f32_16x16x32_bf16(aS, bS[ct], accs[ct], 0, 0, 0);
        } else {
#pragma unroll
            for (int ct = 0; ct < 4; ++ct)
                accs[ct] = __builtin_amdgcn_mfma_f32_16x16x32_bf16(aS, bG[ct], accs[ct], 0, 0, 0);
        }
    }

    // ---- epilogue: C/D layout row=(q*4+r), col=d16 ----
#pragma unroll
    for (int r = 0; r < 4; ++r) {
        int node = base + q * 4 + r;
        if (node < N) {
            float rn = 1.0f / fmaxf((float)cnt[node], 1.0f);
#pragma unroll
            for (int ct = 0; ct < 4; ++ct) {
                agg[(size_t)node * 128 + ct * 16 + d16]      = f2bf(accg[ct][r]);
                agg[(size_t)node * 128 + 64 + ct * 16 + d16] = f2bf(accs[ct][r] * rn);
            }
        }
    }
}

// ===================== fallback scalar gathers (ws-size guard) =====================
// NOTE: offs includes one self slot per node; fallbacks read only the first
// cnt[] entries of each node's range, so they remain correct.
__device__ __forceinline__ void xor_reduce8(float4& a, float4& b) {
    a.x += __shfl_xor(a.x, 16, 64); a.y += __shfl_xor(a.y, 16, 64);
    a.z += __shfl_xor(a.z, 16, 64); a.w += __shfl_xor(a.w, 16, 64);
    b.x += __shfl_xor(b.x, 16, 64); b.y += __shfl_xor(b.y, 16, 64);
    b.z += __shfl_xor(b.z, 16, 64); b.w += __shfl_xor(b.w, 16, 64);
    a.x += __shfl_xor(a.x, 32, 64); a.y += __shfl_xor(a.y, 32, 64);
    a.z += __shfl_xor(a.z, 32, 64); a.w += __shfl_xor(a.w, 32, 64);
    b.x += __shfl_xor(b.x, 32, 64); b.y += __shfl_xor(b.y, 32, 64);
    b.z += __shfl_xor(b.z, 32, 64); b.w += __shfl_xor(b.w, 32, 64);
}

__device__ __forceinline__ float red16(float v) {
    v += __shfl_xor(v, 1, 64);
    v += __shfl_xor(v, 2, 64);
    v += __shfl_xor(v, 4, 64);
    v += __shfl_xor(v, 8, 64);
    return v;
}

__global__ void k_gather1_f32(const float* __restrict__ x, const int* __restrict__ csr,
                              const int* __restrict__ offs, const int* __restrict__ cnt,
                              const float* __restrict__ dinv,
                              unsigned short* __restrict__ agg, int N) {
    int lane = threadIdx.x & 63;
    int wave = threadIdx.x >> 6;
    int node = blockIdx.x * 4 + wave;
    if (node >= N) return;
    int c = lane & 15, grp = lane >> 4;

    int st = offs[node];
    int cn = cnt[node];
    float di = dinv[node];

    float4 aA = {0.f, 0.f, 0.f, 0.f}, aB = {0.f, 0.f, 0.f, 0.f};
    for (int e = 0; e < cn; e += 8) {
        int i0 = e + grp, i1 = e + 4 + grp;
        float m0 = (i0 < cn) ? 1.f : 0.f;
        float m1 = (i1 < cn) ? 1.f : 0.f;
        int s0 = csr[st + (i0 < cn ? i0 : cn - 1)];
        int s1 = csr[st + (i1 < cn ? i1 : cn - 1)];
        float w0 = m0 * dinv[s0];
        float w1 = m1 * dinv[s1];
        float4 v0 = *(const float4*)&x[(size_t)s0 * 64 + 4 * c];
        float4 v1 = *(const float4*)&x[(size_t)s1 * 64 + 4 * c];
        aA.x += w0 * v0.x + w1 * v1.x; aA.y += w0 * v0.y + w1 * v1.y;
        aA.z += w0 * v0.z + w1 * v1.z; aA.w += w0 * v0.w + w1 * v1.w;
        aB.x += m0 * v0.x + m1 * v1.x; aB.y += m0 * v0.y + m1 * v1.y;
        aB.z += m0 * v0.z + m1 * v1.z; aB.w += m0 * v0.w + m1 * v1.w;
    }
    xor_reduce8(aA, aB);

    if (grp == 0) {
        float4 sq = *(const float4*)&x[(size_t)node * 64 + 4 * c];
        float d2 = di * di;
        ushort4 o;
        o.x = f2bf(di * aA.x + d2 * sq.x); o.y = f2bf(di * aA.y + d2 * sq.y);
        o.z = f2bf(di * aA.z + d2 * sq.z); o.w = f2bf(di * aA.w + d2 * sq.w);
        *(ushort4*)&agg[(size_t)node * 128 + 4 * c] = o;
    } else if (grp == 1) {
        float rn = 1.0f / fmaxf((float)cn, 1.0f);
        ushort4 o;
        o.x = f2bf(aB.x * rn); o.y = f2bf(aB.y * rn);
        o.z = f2bf(aB.z * rn); o.w = f2bf(aB.w * rn);
        *(ushort4*)&agg[(size_t)node * 128 + 64 + 4 * c] = o;
    }
}

__global__ void k_gather2(const unsigned short* __restrict__ gs, const int* __restrict__ csr,
                          const int* __restrict__ offs, const int* __restrict__ cnt,
                          const float* __restrict__ dinv,
                          unsigned short* __restrict__ agg, int N) {
    int lane = threadIdx.x & 63;
    int wave = threadIdx.x >> 6;
    int node = blockIdx.x * 4 + wave;
    if (node >= N) return;
    int c = lane & 15, grp = lane >> 4;

    int st = offs[node];
    int cn = cnt[node];
    float di = dinv[node];

    float4 aC = {0.f, 0.f, 0.f, 0.f}, aD = {0.f, 0.f, 0.f, 0.f};
    for (int e = 0; e < cn; e += 8) {
        int i0 = e + grp, i1 = e + 4 + grp;
        float m0 = (i0 < cn) ? 1.f : 0.f;
        float m1 = (i1 < cn) ? 1.f : 0.f;
        int s0 = csr[st + (i0 < cn ? i0 : cn - 1)];
        int s1 = csr[st + (i1 < cn ? i1 : cn - 1)];
        float w0 = m0 * dinv[s0];
        float w1 = m1 * dinv[s1];
        const unsigned short* p0 = gs + (size_t)s0 * 128 + 4 * c;
        const unsigned short* p1 = gs + (size_t)s1 * 128 + 4 * c;
        ushort4 g0u = *(const ushort4*)p0;
        ushort4 g1u = *(const ushort4*)p1;
        ushort4 t0u = *(const ushort4*)(p0 + 64);
        ushort4 t1u = *(const ushort4*)(p1 + 64);
        aC.x += w0 * bf2f(g0u.x) + w1 * bf2f(g1u.x);
        aC.y += w0 * bf2f(g0u.y) + w1 * bf2f(g1u.y);
        aC.z += w0 * bf2f(g0u.z) + w1 * bf2f(g1u.z);
        aC.w += w0 * bf2f(g0u.w) + w1 * bf2f(g1u.w);
        aD.x += m0 * bf2f(t0u.x) + m1 * bf2f(t1u.x);
        aD.y += m0 * bf2f(t0u.y) + m1 * bf2f(t1u.y);
        aD.z += m0 * bf2f(t0u.z) + m1 * bf2f(t1u.z);
        aD.w += m0 * bf2f(t0u.w) + m1 * bf2f(t1u.w);
    }
    xor_reduce8(aC, aD);

    if (grp == 0) {
        ushort4 su = *(const ushort4*)&gs[(size_t)node * 128 + 4 * c];
        float d2 = di * di;
        ushort4 o;
        o.x = f2bf(di * aC.x + d2 * bf2f(su.x));
        o.y = f2bf(di * aC.y + d2 * bf2f(su.y));
        o.z = f2bf(di * aC.z + d2 * bf2f(su.z));
        o.w = f2bf(di * aC.w + d2 * bf2f(su.w));
        *(ushort4*)&agg[(size_t)node * 128 + 4 * c] = o;
    } else if (grp == 1) {
        float rn = 1.0f / fmaxf((float)cn, 1.0f);
        ushort4 o;
        o.x = f2bf(aD.x * rn); o.y = f2bf(aD.y * rn);
        o.z = f2bf(aD.z * rn); o.w = f2bf(aD.w * rn);
        *(ushort4*)&agg[(size_t)node * 128 + 64 + 4 * c] = o;
    }
}

// Layer-1 GEMMs via MFMA. use_xb selects bf16 or fp32 x source (uniform).
__launch_bounds__(512, 1)
__global__ void k_gemm1(const unsigned short* __restrict__ agg,
                        const unsigned short* __restrict__ xb,
                        const float* __restrict__ xf, int use_xb,
                        const float* __restrict__ W1, const float* __restrict__ b1,
                        const float* __restrict__ Wl1, const float* __restrict__ bl1,
                        const float* __restrict__ Wr1,
                        unsigned short* __restrict__ buf1, int N) {
    alignas(16) __shared__ unsigned short sW[3][4096];
    int t = threadIdx.x;
    for (int i = t; i < 1536; i += 512) {
        int m = i >> 9;
        int rem = i & 511;
        int f = rem >> 6;
        int L = rem & 63;
        int kb = (f >> 2) * 32 + (L >> 4) * 8;
        int o = (f & 3) * 16 + (L & 15);
        const float* Wsrc = (m == 0) ? W1 : (m == 1) ? Wl1 : Wr1;
        unsigned short* dst = &sW[m][f * 512 + L * 8];
        #pragma unroll
        for (int j = 0; j < 8; ++j) dst[j] = f2bf(Wsrc[(kb + j) * 64 + o]);
    }
    __syncthreads();

    int lane = t & 63;
    int wave = t >> 6;
    int quad = lane >> 4;
    int n16 = lane & 15;
    int base = blockIdx.x * 128 + wave * 16;
    if (base >= N) return;

    int nm = base + n16;
    if (nm >= N) nm = N - 1;
    const unsigned short* ar = agg + (size_t)nm * 128;

    {
        short8 a0 = *(const short8*)(ar + quad * 8);
        short8 a1 = *(const short8*)(ar + 32 + quad * 8);
        floatx4 g0 = {0.f, 0.f, 0.f, 0.f}, g1 = g0, g2 = g0, g3 = g0;
        g0 = __builtin_amdgcn_mfma_f32_16x16x32_bf16(a0, *(const short8*)&sW[0][0 * 512 + lane * 8], g0, 0, 0, 0);
        g0 = __builtin_amdgcn_mfma_f32_16x16x32_bf16(a1, *(const short8*)&sW[0][4 * 512 + lane * 8], g0, 0, 0, 0);
        g1 = __builtin_amdgcn_mfma_f32_16x16x32_bf16(a0, *(const short8*)&sW[0][1 * 512 + lane * 8], g1, 0, 0, 0);
        g1 = __builtin_amdgcn_mfma_f32_16x16x32_bf16(a1, *(const short8*)&sW[0][5 * 512 + lane * 8], g1, 0, 0, 0);
        g2 = __builtin_amdgcn_mfma_f32_16x16x32_bf16(a0, *(const short8*)&sW[0][2 * 512 + lane * 8], g2, 0, 0, 0);
        g2 = __builtin_amdgcn_mfma_f32_16x16x32_bf16(a1, *(const short8*)&sW[0][6 * 512 + lane * 8], g2, 0, 0, 0);
        g3 = __builtin_amdgcn_mfma_f32_16x16x32_bf16(a0, *(const short8*)&sW[0][3 * 512 + lane * 8], g3, 0, 0, 0);
        g3 = __builtin_amdgcn_mfma_f32_16x16x32_bf16(a1, *(const short8*)&sW[0][7 * 512 + lane * 8], g3, 0, 0, 0);
        floatx4 gt[4] = {g0, g1, g2, g3};
        #pragma unroll
        for (int nt = 0; nt < 4; ++nt) {
            float bg = b1[nt * 16 + n16];
            #pragma unroll
            for (int r = 0; r < 4; ++r) {
                int node = base + quad * 4 + r;
                if (node < N)
                    buf1[(size_t)node * 128 + nt * 16 + n16] = f2bf(fmaxf(gt[nt][r] + bg, 0.f));
            }
        }
    }

    {
        short8 a0 = *(const short8*)(ar + 64 + quad * 8);
        short8 a1 = *(const short8*)(ar + 96 + quad * 8);
        short8 ax0, ax1;
        if (use_xb) {
            ax0 = *(const short8*)&xb[(size_t)nm * 64 + quad * 8];
            ax1 = *(const short8*)&xb[(size_t)nm * 64 + 32 + quad * 8];
        } else {
            float4 xq0 = *(const float4*)&xf[(size_t)nm * 64 + quad * 8];
            float4 xq1 = *(const float4*)&xf[(size_t)nm * 64 + quad * 8 + 4];
            float4 xq2 = *(const float4*)&xf[(size_t)nm * 64 + 32 + quad * 8];
            float4 xq3 = *(const float4*)&xf[(size_t)nm * 64 + 32 + quad * 8 + 4];
            ax0[0] = (short)f2bf(xq0.x); ax0[1] = (short)f2bf(xq0.y);
            ax0[2] = (short)f2bf(xq0.z); ax0[3] = (short)f2bf(xq0.w);
            ax0[4] = (short)f2bf(xq1.x); ax0[5] = (short)f2bf(xq1.y);
            ax0[6] = (short)f2bf(xq1.z); ax0[7] = (short)f2bf(xq1.w);
            ax1[0] = (short)f2bf(xq2.x); ax1[1] = (short)f2bf(xq2.y);
            ax1[2] = (short)f2bf(xq2.z); ax1[3] = (short)f2bf(xq2.w);
            ax1[4] = (short)f2bf(xq3.x); ax1[5] = (short)f2bf(xq3.y);
            ax1[6] = (short)f2bf(xq3.z); ax1[7] = (short)f2bf(xq3.w);
        }

        floatx4 s0 = {0.f, 0.f, 0.f, 0.f}, s1 = s0, s2 = s0, s3 = s0;
        s0 = __builtin_amdgcn_mfma_f32_16x16x32_bf16(a0, *(const short8*)&sW[1][0 * 512 + lane * 8], s0, 0, 0, 0);
        s0 = __builtin_amdgcn_mfma_f32_16x16x32_bf16(a1, *(const short8*)&sW[1][4 * 512 + lane * 8], s0, 0, 0, 0);
        s0 = __builtin_amdgcn_mfma_f32_16x16x32_bf16(ax0, *(const short8*)&sW[2][0 * 512 + lane * 8], s0, 0, 0, 0);
        s0 = __builtin_amdgcn_mfma_f32_16x16x32_bf16(ax1, *(const short8*)&sW[2][4 * 512 + lane * 8], s0, 0, 0, 0);
        s1 = __builtin_amdgcn_mfma_f32_16x16x32_bf16(a0, *(const short8*)&sW[1][1 * 512 + lane * 8], s1, 0, 0, 0);
        s1 = __builtin_amdgcn_mfma_f32_16x16x32_bf16(a1, *(const short8*)&sW[1][5 * 512 + lane * 8], s1, 0, 0, 0);
        s1 = __builtin_amdgcn_mfma_f32_16x16x32_bf16(ax0, *(const short8*)&sW[2][1 * 512 + lane * 8], s1, 0, 0, 0);
        s1 = __builtin_amdgcn_mfma_f32_16x16x32_bf16(ax1, *(const short8*)&sW[2][5 * 512 + lane * 8], s1, 0, 0, 0);
        s2 = __builtin_amdgcn_mfma_f32_16x16x32_bf16(a0, *(const short8*)&sW[1][2 * 512 + lane * 8], s2, 0, 0, 0);
        s2 = __builtin_amdgcn_mfma_f32_16x16x32_bf16(a1, *(const short8*)&sW[1][6 * 512 + lane * 8], s2, 0, 0, 0);
        s2 = __builtin_amdgcn_mfma_f32_16x16x32_bf16(ax0, *(const short8*)&sW[2][2 * 512 + lane * 8], s2, 0, 0, 0);
        s2 = __builtin_amdgcn_mfma_f32_16x16x32_bf16(ax1, *(const short8*)&sW[2][6 * 512 + lane * 8], s2, 0, 0, 0);
        s3 = __builtin_amdgcn_mfma_f32_16x16x32_bf16(a0, *(const short8*)&sW[1][3 * 512 + lane * 8], s3, 0, 0, 0);
        s3 = __builtin_amdgcn_mfma_f32_16x16x32_bf16(a1, *(const short8*)&sW[1][7 * 512 + lane * 8], s3, 0, 0, 0);
        s3 = __builtin_amdgcn_mfma_f32_16x16x32_bf16(ax0, *(const short8*)&sW[2][3 * 512 + lane * 8], s3, 0, 0, 0);
        s3 = __builtin_amdgcn_mfma_f32_16x16x32_bf16(ax1, *(const short8*)&sW[2][7 * 512 + lane * 8], s3, 0, 0, 0);
        floatx4 stl[4] = {s0, s1, s2, s3};
        #pragma unroll
        for (int nt = 0; nt < 4; ++nt) {
            float bs = bl1[nt * 16 + n16];
            #pragma unroll
            for (int r = 0; r < 4; ++r) {
                int node = base + quad * 4 + r;
                if (node < N)
                    buf1[(size_t)node * 128 + 64 + nt * 16 + n16] = f2bf(fmaxf(stl[nt][r] + bs, 0.f));
            }
        }
    }
}

// Layer-2 GEMMs + LN + concat-proj via MFMA (proven in R8).
__launch_bounds__(512, 1)
__global__ void k_gemm2(const unsigned short* __restrict__ agg,
                        const unsigned short* __restrict__ buf1,
                        const float* __restrict__ W2, const float* __restrict__ b2,
                        const float* __restrict__ Wl2, const float* __restrict__ bl2,
                        const float* __restrict__ Wr2,
                        const float* __restrict__ lngG, const float* __restrict__ lnbG,
                        const float* __restrict__ lngS, const float* __restrict__ lnbS,
                        const float* __restrict__ Pw, const float* __restrict__ Pb,
                        float* __restrict__ out, int N) {
    alignas(16) __shared__ unsigned short sW[3][4096];
    alignas(16) __shared__ unsigned short sP[8192];
    alignas(16) __shared__ unsigned short sT[8][16 * 132];
    int t = threadIdx.x;
    for (int i = t; i < 1536; i += 512) {
        int m = i >> 9;
        int rem = i & 511;
        int f = rem >> 6;
        int L = rem & 63;
        int kb = (f >> 2) * 32 + (L >> 4) * 8;
        int o = (f & 3) * 16 + (L & 15);
        const float* Wsrc = (m == 0) ? W2 : (m == 1) ? Wl2 : Wr2;
        unsigned short* dst = &sW[m][f * 512 + L * 8];
        #pragma unroll
        for (int j = 0; j < 8; ++j) dst[j] = f2bf(Wsrc[(kb + j) * 64 + o]);
    }
    for (int i = t; i < 1024; i += 512) {
        int f = i >> 6;
        int L = i & 63;
        int kb = (f >> 2) * 32 + (L >> 4) * 8;
        int o = (f & 3) * 16 + (L & 15);
        unsigned short* dst = &sP[f * 512 + L * 8];
        #pragma unroll
        for (int j = 0; j < 8; ++j) dst[j] = f2bf(Pw[(kb + j) * 64 + o]);
    }
    __syncthreads();

    int lane = t & 63;
    int wave = t >> 6;
    int quad = lane >> 4;
    int n16 = lane & 15;
    int base = blockIdx.x * 128 + wave * 16;
    if (base >= N) return;
    int nm = base + n16;
    if (nm >= N) nm = N - 1;
    const unsigned short* ar = agg + (size_t)nm * 128;
    const unsigned short* br = buf1 + (size_t)nm * 128;
    unsigned short* tw = &sT[wave][0];

    {
        short8 a0 = *(const short8*)(ar + quad * 8);
        short8 a1 = *(const short8*)(ar + 32 + quad * 8);
        floatx4 c0 = {0.f, 0.f, 0.f, 0.f}, c1 = c0, c2 = c0, c3 = c0;
        c0 = __builtin_amdgcn_mfma_f32_16x16x32_bf16(a0, *(const short8*)&sW[0][0 * 512 + lane * 8], c0, 0, 0, 0);
        c0 = __builtin_amdgcn_mfma_f32_16x16x32_bf16(a1, *(const short8*)&sW[0][4 * 512 + lane * 8], c0, 0, 0, 0);
        c1 = __builtin_amdgcn_mfma_f32_16x16x32_bf16(a0, *(const short8*)&sW[0][1 * 512 + lane * 8], c1, 0, 0, 0);
        c1 = __builtin_amdgcn_mfma_f32_16x16x32_bf16(a1, *(const short8*)&sW[0][5 * 512 + lane * 8], c1, 0, 0, 0);
        c2 = __builtin_amdgcn_mfma_f32_16x16x32_bf16(a0, *(const short8*)&sW[0][2 * 512 + lane * 8], c2, 0, 0, 0);
        c2 = __builtin_amdgcn_mfma_f32_16x16x32_bf16(a1, *(const short8*)&sW[0][6 * 512 + lane * 8], c2, 0, 0, 0);
        c3 = __builtin_amdgcn_mfma_f32_16x16x32_bf16(a0, *(const short8*)&sW[0][3 * 512 + lane * 8], c3, 0, 0, 0);
        c3 = __builtin_amdgcn_mfma_f32_16x16x32_bf16(a1, *(const short8*)&sW[0][7 * 512 + lane * 8], c3, 0, 0, 0);

        float bv0 = b2[n16], bv1 = b2[16 + n16], bv2 = b2[32 + n16], bv3 = b2[48 + n16];
        float gv0 = lngG[n16], gv1 = lngG[16 + n16], gv2 = lngG[32 + n16], gv3 = lngG[48 + n16];
        float ev0 = lnbG[n16], ev1 = lnbG[16 + n16], ev2 = lnbG[32 + n16], ev3 = lnbG[48 + n16];
        #pragma unroll
        for (int r = 0; r < 4; ++r) {
            float z0 = c0[r] + bv0, z1 = c1[r] + bv1, z2 = c2[r] + bv2, z3 = c3[r] + bv3;
            float s = red16(z0 + z1 + z2 + z3);
            float q = red16(z0 * z0 + z1 * z1 + z2 * z2 + z3 * z3);
            float mu = s * (1.0f / 64.0f);
            float var = fmaxf(q * (1.0f / 64.0f) - mu * mu, 0.0f);
            float rs = rsqrtf(var + 1e-5f);
            unsigned short* row = tw + (quad * 4 + r) * 132;
            row[n16]      = f2bf((z0 - mu) * rs * gv0 + ev0);
            row[16 + n16] = f2bf((z1 - mu) * rs * gv1 + ev1);
            row[32 + n16] = f2bf((z2 - mu) * rs * gv2 + ev2);
            row[48 + n16] = f2bf((z3 - mu) * rs * gv3 + ev3);
        }
    }

    {
        short8 a0 = *(const short8*)(ar + 64 + quad * 8);
        short8 a1 = *(const short8*)(ar + 96 + quad * 8);
        short8 v0 = *(const short8*)(br + 64 + quad * 8);
        short8 v1 = *(const short8*)(br + 96 + quad * 8);
        floatx4 c0 = {0.f, 0.f, 0.f, 0.f}, c1 = c0, c2 = c0, c3 = c0;
        c0 = __builtin_amdgcn_mfma_f32_16x16x32_bf16(a0, *(const short8*)&sW[1][0 * 512 + lane * 8], c0, 0, 0, 0);
        c0 = __builtin_amdgcn_mfma_f32_16x16x32_bf16(a1, *(const short8*)&sW[1][4 * 512 + lane * 8], c0, 0, 0, 0);
        c0 = __builtin_amdgcn_mfma_f32_16x16x32_bf16(v0, *(const short8*)&sW[2][0 * 512 + lane * 8], c0, 0, 0, 0);
        c0 = __builtin_amdgcn_mfma_f32_16x16x32_bf16(v1, *(const short8*)&sW[2][4 * 512 + lane * 8], c0, 0, 0, 0);
        c1 = __builtin_amdgcn_mfma_f32_16x16x32_bf16(a0, *(const short8*)&sW[1][1 * 512 + lane * 8], c1, 0, 0, 0);
        c1 = __builtin_amdgcn_mfma_f32_16x16x32_bf16(a1, *(const short8*)&sW[1][5 * 512 + lane * 8], c1, 0, 0, 0);
        c1 = __builtin_amdgcn_mfma_f32_16x16x32_bf16(v0, *(const short8*)&sW[2][1 * 512 + lane * 8], c1, 0, 0, 0);
        c1 = __builtin_amdgcn_mfma_f32_16x16x32_bf16(v1, *(const short8*)&sW[2][5 * 512 + lane * 8], c1, 0, 0, 0);
        c2 = __builtin_amdgcn_mfma_f32_16x16x32_bf16(a0, *(const short8*)&sW[1][2 * 512 + lane * 8], c2, 0, 0, 0);
        c2 = __builtin_amdgcn_mfma_f32_16x16x32_bf16(a1, *(const short8*)&sW[1][6 * 512 + lane * 8], c2, 0, 0, 0);
        c2 = __builtin_amdgcn_mfma_f32_16x16x32_bf16(v0, *(const short8*)&sW[2][2 * 512 + lane * 8], c2, 0, 0, 0);
        c2 = __builtin_amdgcn_mfma_f32_16x16x32_bf16(v1, *(const short8*)&sW[2][6 * 512 + lane * 8], c2, 0, 0, 0);
        c3 = __builtin_amdgcn_mfma_f32_16x16x32_bf16(a0, *(const short8*)&sW[1][3 * 512 + lane * 8], c3, 0, 0, 0);
        c3 = __builtin_amdgcn_mfma_f32_16x16x32_bf16(a1, *(const short8*)&sW[1][7 * 512 + lane * 8], c3, 0, 0, 0);
        c3 = __builtin_amdgcn_mfma_f32_16x16x32_bf16(v0, *(const short8*)&sW[2][3 * 512 + lane * 8], c3, 0, 0, 0);
        c3 = __builtin_amdgcn_mfma_f32_16x16x32_bf16(v1, *(const short8*)&sW[2][7 * 512 + lane * 8], c3, 0, 0, 0);

        float bv0 = bl2[n16], bv1 = bl2[16 + n16], bv2 = bl2[32 + n16], bv3 = bl2[48 + n16];
        float gv0 = lngS[n16], gv1 = lngS[16 + n16], gv2 = lngS[32 + n16], gv3 = lngS[48 + n16];
        float ev0 = lnbS[n16], ev1 = lnbS[16 + n16], ev2 = lnbS[32 + n16], ev3 = lnbS[48 + n16];
        #pragma unroll
        for (int r = 0; r < 4; ++r) {
            float z0 = c0[r] + bv0, z1 = c1[r] + bv1, z2 = c2[r] + bv2, z3 = c3[r] + bv3;
            float s = red16(z0 + z1 + z2 + z3);
            float q = red16(z0 * z0 + z1 * z1 + z2 * z2 + z3 * z3);
            float mu = s * (1.0f / 64.0f);
            float var = fmaxf(q * (1.0f / 64.0f) - mu * mu, 0.0f);
            float rs = rsqrtf(var + 1e-5f);
            unsigned short* row = tw + (quad * 4 + r) * 132 + 64;
            row[n16]      = f2bf((z0 - mu) * rs * gv0 + ev0);
            row[16 + n16] = f2bf((z1 - mu) * rs * gv1 + ev1);
            row[32 + n16] = f2bf((z2 - mu) * rs * gv2 + ev2);
            row[48 + n16] = f2bf((z3 - mu) * rs * gv3 + ev3);
        }
    }

    floatx4 o0 = {0.f, 0.f, 0.f, 0.f}, o1 = o0, o2 = o0, o3 = o0;
    #pragma unroll
    for (int ks = 0; ks < 4; ++ks) {
        const unsigned short* ap = tw + n16 * 132 + ks * 32 + quad * 8;
        short4v lo = *(const short4v*)ap;
        short4v hi = *(const short4v*)(ap + 4);
        short8 af;
        af[0] = lo[0]; af[1] = lo[1]; af[2] = lo[2]; af[3] = lo[3];
        af[4] = hi[0]; af[5] = hi[1]; af[6] = hi[2]; af[7] = hi[3];
        o0 = __builtin_amdgcn_mfma_f32_16x16x32_bf16(af, *(const short8*)&sP[(ks * 4 + 0) * 512 + lane * 8], o0, 0, 0, 0);
        o1 = __builtin_amdgcn_mfma_f32_16x16x32_bf16(af, *(const short8*)&sP[(ks * 4 + 1) * 512 + lane * 8], o1, 0, 0, 0);
        o2 = __builtin_amdgcn_mfma_f32_16x16x32_bf16(af, *(const short8*)&sP[(ks * 4 + 2) * 512 + lane * 8], o2, 0, 0, 0);
        o3 = __builtin_amdgcn_mfma_f32_16x16x32_bf16(af, *(const short8*)&sP[(ks * 4 + 3) * 512 + lane * 8], o3, 0, 0, 0);
    }
    float p0 = Pb[n16], p1 = Pb[16 + n16], p2 = Pb[32 + n16], p3 = Pb[48 + n16];
    floatx4 ot[4] = {o0, o1, o2, o3};
    float pv[4] = {p0, p1, p2, p3};
    #pragma unroll
    for (int nt = 0; nt < 4; ++nt) {
        #pragma unroll
        for (int r = 0; r < 4; ++r) {
            int node = base + quad * 4 + r;
            if (node < N) out[(size_t)node * 64 + nt * 16 + n16] = ot[nt][r] + pv[nt];
        }
    }
}

extern "C" void kernel_launch(void* const* d_in, const int* in_sizes, int n_in,
                              void* d_out, int out_size, void* d_ws, size_t ws_size,
                              hipStream_t stream) {
    const float* x        = (const float*)d_in[0];
    const int*   ei       = (const int*)d_in[1];
    const float* gcn_w1   = (const float*)d_in[2];
    const float* gcn_b1   = (const float*)d_in[3];
    const float* gcn_w2   = (const float*)d_in[4];
    const float* gcn_b2   = (const float*)d_in[5];
    const float* sage_wl1 = (const float*)d_in[6];
    const float* sage_bl1 = (const float*)d_in[7];
    const float* sage_wr1 = (const float*)d_in[8];
    const float* sage_wl2 = (const float*)d_in[9];
    const float* sage_bl2 = (const float*)d_in[10];
    const float* sage_wr2 = (const float*)d_in[11];
    const float* gcn_ln_g = (const float*)d_in[12];
    const float* gcn_ln_b = (const float*)d_in[13];
    const float* sage_ln_g = (const float*)d_in[14];
    const float* sage_ln_b = (const float*)d_in[15];
    const float* proj_w   = (const float*)d_in[16];
    const float* proj_b   = (const float*)d_in[17];
    float* out = (float*)d_out;

    const int N = in_sizes[0] / 64;
    const int E = in_sizes[1] / 2;
    const int B = (N + SCAN_CHUNK - 1) / SCAN_CHUNK;

    char* w = (char*)d_ws;
    size_t off = 0;
    auto alloc = [&](size_t bytes) -> void* {
        void* p = w + off;
        off = (off + bytes + 255) & ~(size_t)255;
        return p;
    };
    int*            cnt       = (int*)alloc((size_t)N * 4);
    int*            offs      = (int*)alloc((size_t)(N + 1) * 4);
    float*          dinv      = (float*)alloc((size_t)N * 4);
    int*            blockSums = (int*)alloc((size_t)(B + 1) * 4);
    int*            csr       = (int*)alloc((size_t)(E + N + 64) * 4);
    unsigned short* agg       = (unsigned short*)alloc((size_t)N * 128 * 2);  // also aliases rank (dead before gather1)
    unsigned short* buf1      = (unsigned short*)alloc((size_t)N * 128 * 2);
    size_t off_nonew = off;
    unsigned int*   pk        = (unsigned int*)alloc((size_t)(E + N + 64) * 4);
    unsigned short* xb        = (unsigned short*)alloc((size_t)N * 64 * 2);
    int use_new = (off <= ws_size) ? 1 : 0;
    if (!use_new) off = off_nonew;
    int* rank = (int*)agg;  // E*4 = 5MB <= 25.6MB agg region
    (void)n_in; (void)out_size;

    hipMemsetAsync(cnt, 0, (size_t)N * 4, stream);

    int e4Blocks = ((E + 3) / 4 + 255) / 256;
    int x8Blocks = ((N * 64 + 7) / 8 + 255) / 256;
    int cntBlocks = use_new ? max(e4Blocks, x8Blocks) : e4Blocks;
    k_count<<<cntBlocks, 256, 0, stream>>>(ei, E, cnt, rank, x, xb, N * 64, use_new);
    k_scan_reduce<<<B, 256, 0, stream>>>(cnt, N, blockSums);
    k_scan_spine<<<1, 64, 0, stream>>>(blockSums, B);
    k_scan_write<<<B, 256, 0, stream>>>(cnt, N, blockSums, offs, dinv);
    k_fill<<<e4Blocks, 256, 0, stream>>>(ei, E, offs, rank, cnt, dinv, csr, pk, use_new, N);

    if (use_new) {
        k_gatherM<64><<<(N + 63) / 64, 256, 0, stream>>>(xb, csr, pk, offs, cnt, agg, N);
        k_gemm1<<<(N + 127) / 128, 512, 0, stream>>>(agg, xb, x, 1, gcn_w1, gcn_b1,
                                                     sage_wl1, sage_bl1, sage_wr1, buf1, N);
        k_gatherM<128><<<(N + 63) / 64, 256, 0, stream>>>(buf1, csr, pk, offs, cnt, agg, N);
    } else {
        k_gather1_f32<<<(N + 3) / 4, 256, 0, stream>>>(x, csr, offs, cnt, dinv, agg, N);
        k_gemm1<<<(N + 127) / 128, 512, 0, stream>>>(agg, xb, x, 0, gcn_w1, gcn_b1,
                                                     sage_wl1, sage_bl1, sage_wr1, buf1, N);
        k_gather2<<<(N + 3) / 4, 256, 0, stream>>>(buf1, csr, offs, cnt, dinv, agg, N);
    }
    k_gemm2<<<(N + 127) / 128, 512, 0, stream>>>(agg, buf1, gcn_w2, gcn_b2,
                                                 sage_wl2, sage_bl2, sage_wr2,
                                                 gcn_ln_g, gcn_ln_b, sage_ln_g, sage_ln_b,
                                                 proj_w, proj_b, out, N);
}